// Round 9
// baseline (232.541 us; speedup 1.0000x reference)
//
#include <hip/hip_runtime.h>

#define N_NODES 50000
#define N_EDGES 800000
#define F_IN    512
#define HID     128
#define OUT_F   20
#define CAP     48           // max in-degree capacity (mean 16, 8 sigma headroom)

#define BM  32

typedef __bf16 bf16x8 __attribute__((ext_vector_type(8)));
typedef float  f32x4  __attribute__((ext_vector_type(4)));

// ---------------- CSR-by-destination via fixed-capacity buckets ----------------

// one atomic per edge; payload packed into a single 8B store
__global__ void k_fillb(const int* __restrict__ row, const int* __restrict__ col,
                        const float* __restrict__ ew, int* __restrict__ cursor,
                        uint2* __restrict__ packed) {
    int e = blockIdx.x * blockDim.x + threadIdx.x;
    if (e < N_EDGES) {
        int c = col[e];
        int pos = atomicAdd(&cursor[c], 1);
        packed[pos] = make_uint2((unsigned)row[e], __float_as_uint(ew[e]));
    }
}

// deg = 1 + sum(w) over bucket (sequential, no atomics); dinv = rsqrt(deg); cnt saved
__global__ void k_degdinv(const int* __restrict__ cursor, const uint2* __restrict__ packed,
                          int* __restrict__ cnt, float* __restrict__ dinv) {
    int i = blockIdx.x * blockDim.x + threadIdx.x;
    if (i < N_NODES) {
        int n = cursor[i] - i * CAP;
        cnt[i] = n;
        const uint2* seg = packed + (size_t)i * CAP;
        float d = 1.0f;
        for (int k = 0; k < n; ++k) d += __uint_as_float(seg[k].y);
        dinv[i] = rsqrtf(d);   // d >= 1 always
    }
}

// ---------------- prep: W1 -> frag-ready permuted bf16 + cursor init (fused) ----------
// w1p index: (((kk*4 + g)*128 + cc)*8 + j); B-frag elem j of lane group g covers
// k = kk*32 + g*4 + (j&3) + 16*(j>>2), column cc.

__global__ void k_prep(const float* __restrict__ W1, __bf16* __restrict__ w1p,
                       int* __restrict__ cursor) {
    int gidx = blockIdx.x * blockDim.x + threadIdx.x;
    if (gidx < F_IN * HID) {
        int k  = gidx >> 7;
        int cc = gidx & (HID - 1);
        int kk = k >> 5;
        int r  = k & 31;
        int g  = (r & 15) >> 2;
        int j  = (r & 3) + ((r >> 4) << 2);
        w1p[((((size_t)kk * 4 + g) * 128 + cc) << 3) + j] = (__bf16)W1[gidx];
    }
    if (gidx < N_NODES) cursor[gidx] = gidx * CAP;
}

// ---------------- layer 1 GEMM (MFMA bf16): hb = bf16(x @ W1) ----------------
// Barrier-free, LDS-free. 32x128 block tile, 4 waves 2x2, wave = 16x64 (1x4 frags).
// Prefetch depth 2 with RAW fp32 ring buffers (alo/ahi[3]): the fp32->bf16 cvt
// happens only at CONSUME time, so issued loads have no dependent VALU ops and
// stay in flight (counted vmcnt, not vmcnt(0)). B is bf16 already (no cvt).
// __launch_bounds__(256,4): VGPR cap 128 so the ring (~100 regs) survives regalloc.
// Loads unconditional (row clamped); stores guarded.

__global__ __launch_bounds__(256, 4) void k_gemm1_mfma(const float* __restrict__ x,
                                                       const __bf16* __restrict__ w1p,
                                                       __bf16* __restrict__ hb) {
    const int tid  = threadIdx.x;
    const int lane = tid & 63;
    const int wid  = tid >> 6;
    const int wm   = wid >> 1;            // row block of 16
    const int wn   = wid & 1;             // col block of 64
    const int r0   = blockIdx.x * BM;
    const int g    = lane >> 4;           // k-group 0..3
    const int l15  = lane & 15;

    int rowi = r0 + wm * 16 + l15;
    if (rowi >= N_NODES) rowi = N_NODES - 1;   // clamp -> unconditional loads
    const float* px = x + (size_t)rowi * F_IN + g * 4;

    f32x4 acc[4] = {};
    float4 alo[3], ahi[3];
    bf16x8 b[3][4];

    auto loadA = [&](int kk, int buf) {
        alo[buf] = *(const float4*)(px + kk * 32);        // k = g*4 + 0..3
        ahi[buf] = *(const float4*)(px + kk * 32 + 16);   // k = g*4 + 16..19
    };
    auto loadB = [&](int kk, int buf) {
#pragma unroll
        for (int ni = 0; ni < 4; ++ni) {
            int cc = wn * 64 + ni * 16 + l15;
            b[buf][ni] = *(const bf16x8*)(w1p + ((((size_t)kk * 4 + g) * 128 + cc) << 3));
        }
    };

    loadA(0, 0); loadB(0, 0);
    loadA(1, 1); loadB(1, 1);
#pragma unroll
    for (int kk = 0; kk < 16; ++kk) {
        const int cur = kk % 3;
        if (kk < 14) {
            const int nb = (kk + 2) % 3;
            loadA(kk + 2, nb);
            loadB(kk + 2, nb);
        }
        // convert at consume time (data landed 2 steps ago)
        union { __bf16 h[8]; bf16x8 v; } u;
        u.h[0] = (__bf16)alo[cur].x; u.h[1] = (__bf16)alo[cur].y;
        u.h[2] = (__bf16)alo[cur].z; u.h[3] = (__bf16)alo[cur].w;
        u.h[4] = (__bf16)ahi[cur].x; u.h[5] = (__bf16)ahi[cur].y;
        u.h[6] = (__bf16)ahi[cur].z; u.h[7] = (__bf16)ahi[cur].w;
#pragma unroll
        for (int ni = 0; ni < 4; ++ni)
            acc[ni] = __builtin_amdgcn_mfma_f32_16x16x32_bf16(
                u.v, b[cur][ni], acc[ni], 0, 0, 0);
    }

    // epilogue: C/D col=lane&15, row=(lane>>4)*4+reg
    const int rb = r0 + wm * 16 + (g << 2);
#pragma unroll
    for (int rr = 0; rr < 4; ++rr) {
        int gr = rb + rr;
        if (gr < N_NODES) {
#pragma unroll
            for (int ni = 0; ni < 4; ++ni) {
                int cc = wn * 64 + ni * 16 + l15;
                hb[(size_t)gr * HID + cc] = (__bf16)acc[ni][rr];
            }
        }
    }
}

// ---------------- layer 1 aggregation: 1 wave per node, bf16x2 packed, on-the-fly norm --

__device__ inline float blo(unsigned v) { union { unsigned u; float f; } c; c.u = v << 16; return c.f; }
__device__ inline float bhi(unsigned v) { union { unsigned u; float f; } c; c.u = v & 0xffff0000u; return c.f; }

__global__ __launch_bounds__(128) void k_agg1(const uint2* __restrict__ packed,
                                              const int* __restrict__ cnt,
                                              const __bf16* __restrict__ hb,
                                              const float* __restrict__ dinv,
                                              const float* __restrict__ b1,
                                              float* __restrict__ h1) {
    __shared__ int   sr[2][64];
    __shared__ float sn[2][64];
    const int w    = threadIdx.x >> 6;
    const int lane = threadIdx.x & 63;
    const int c    = blockIdx.x * 2 + w;
    const unsigned* hbu = (const unsigned*)hb;

    float dic = dinv[c];
    unsigned sv = hbu[((size_t)c << 6) + lane];
    float a0 = dic * dic * blo(sv);
    float a1 = dic * dic * bhi(sv);
    int n = cnt[c];
    const uint2* seg = packed + (size_t)c * CAP;
    for (int base = 0; base < n; base += 64) {
        int m = n - base; if (m > 64) m = 64;
        if (lane < m) {                       // wave-synchronous, no barrier
            uint2 pv = seg[base + lane];
            sr[w][lane] = (int)pv.x;
            sn[w][lane] = __uint_as_float(pv.y) * dinv[pv.x] * dic;
        }
        for (int t = 0; t < m; ++t) {
            float nm = sn[w][t];
            unsigned v = hbu[((size_t)sr[w][t] << 6) + lane];
            a0 = fmaf(nm, blo(v), a0);
            a1 = fmaf(nm, bhi(v), a1);
        }
    }
    float2 bb = *(const float2*)(b1 + 2 * lane);
    a0 += bb.x; a1 += bb.y;
    float2 o2;
    o2.x = a0 > 0.f ? a0 : 0.f;
    o2.y = a1 > 0.f ? a1 : 0.f;
    *(float2*)(h1 + ((size_t)c << 7) + 2 * lane) = o2;
}

// ---------------- layer 2 GEMM: h2 = h1 @ W2  (50000x128 @ 128x20) ----------------

__global__ __launch_bounds__(256) void k_gemm2(const float* __restrict__ h1,
                                               const float* __restrict__ W2,
                                               float* __restrict__ h2) {
    int g = blockIdx.x * blockDim.x + threadIdx.x;
    int i = g >> 5;
    int j = g & 31;
    if (i >= N_NODES || j >= OUT_F) return;
    float acc = 0.f;
    const float* hr = h1 + (size_t)i * HID;
    for (int k = 0; k < HID; ++k) acc = fmaf(hr[k], W2[k * OUT_F + j], acc);
    h2[(size_t)i * OUT_F + j] = acc;
}

// ---------------- layer 2 aggregation (on-the-fly norm) ----------------

__global__ __launch_bounds__(256) void k_agg2(const uint2* __restrict__ packed,
                                              const int* __restrict__ cnt,
                                              const float* __restrict__ h2,
                                              const float* __restrict__ dinv,
                                              const float* __restrict__ b2,
                                              float* __restrict__ out) {
    int g = blockIdx.x * blockDim.x + threadIdx.x;
    int c = g >> 5;
    int j = g & 31;
    if (c >= N_NODES || j >= OUT_F) return;
    float dic = dinv[c];
    float acc = dic * dic * h2[(size_t)c * OUT_F + j] + b2[j];
    int n = cnt[c];
    const uint2* seg = packed + (size_t)c * CAP;
    for (int k = 0; k < n; ++k) {
        uint2 pv = seg[k];                    // broadcast across lanes
        float nm = __uint_as_float(pv.y) * dinv[pv.x] * dic;
        acc = fmaf(nm, h2[(size_t)pv.x * OUT_F + j], acc);
    }
    out[(size_t)c * OUT_F + j] = acc;
}

// ---------------- launch ----------------

extern "C" void kernel_launch(void* const* d_in, const int* in_sizes, int n_in,
                              void* d_out, int out_size, void* d_ws, size_t ws_size,
                              hipStream_t stream) {
    const float* x  = (const float*)d_in[0];
    const int*   ei = (const int*)d_in[1];       // [2][E]
    const float* ew = (const float*)d_in[2];
    const float* W1 = (const float*)d_in[3];
    const float* b1 = (const float*)d_in[4];
    const float* W2 = (const float*)d_in[5];
    const float* b2 = (const float*)d_in[6];
    float* out = (float*)d_out;

    const int* row = ei;
    const int* col = ei + N_EDGES;

    char* p = (char*)d_ws;
    float* dinv   = (float*)p;  p += (size_t)N_NODES * 4;
    float* h1     = (float*)p;  p += (size_t)N_NODES * HID * 4;
    float* h2     = (float*)p;  p += (size_t)N_NODES * OUT_F * 4;
    __bf16* hb    = (__bf16*)p; p += (size_t)N_NODES * HID * 2;
    __bf16* w1p   = (__bf16*)p; p += (size_t)F_IN * HID * 2;
    int* cursor   = (int*)p;    p += (size_t)N_NODES * 4;
    int* cnt      = (int*)p;    p += (size_t)N_NODES * 4;
    uint2* packed = (uint2*)p;  p += (size_t)N_NODES * CAP * 8;

    // prep (W1 permute + cursor init), then CSR build: one atomic pass into buckets
    k_prep<<<(F_IN * HID + 255) / 256, 256, 0, stream>>>(W1, w1p, cursor);
    k_fillb<<<(N_EDGES + 255) / 256, 256, 0, stream>>>(row, col, ew, cursor, packed);
    k_degdinv<<<(N_NODES + 255) / 256, 256, 0, stream>>>(cursor, packed, cnt, dinv);

    // layer 1
    k_gemm1_mfma<<<(N_NODES + BM - 1) / BM, 256, 0, stream>>>(x, w1p, hb);
    k_agg1<<<N_NODES / 2, 128, 0, stream>>>(packed, cnt, hb, dinv, b1, h1);

    // layer 2
    k_gemm2<<<(N_NODES * 32 + 255) / 256, 256, 0, stream>>>(h1, W2, h2);
    k_agg2<<<(N_NODES * 32 + 255) / 256, 256, 0, stream>>>(packed, cnt, h2, dinv, b2, out);
}

// Round 10
// 231.719 us; speedup vs baseline: 1.0035x; 1.0035x over previous
//
#include <hip/hip_runtime.h>

#define N_NODES 50000
#define N_EDGES 800000
#define F_IN    512
#define HID     128
#define OUT_F   20
#define CAP     48           // max in-degree capacity (mean 16, 8 sigma headroom)

#define BM  32

typedef __bf16 bf16x8 __attribute__((ext_vector_type(8)));
typedef float  f32x4  __attribute__((ext_vector_type(4)));

// ---------------- CSR-by-destination via fixed-capacity buckets ----------------

// one atomic per edge; payload packed into a single 8B store
__global__ void k_fillb(const int* __restrict__ row, const int* __restrict__ col,
                        const float* __restrict__ ew, int* __restrict__ cursor,
                        uint2* __restrict__ packed) {
    int e = blockIdx.x * blockDim.x + threadIdx.x;
    if (e < N_EDGES) {
        int c = col[e];
        int pos = atomicAdd(&cursor[c], 1);
        packed[pos] = make_uint2((unsigned)row[e], __float_as_uint(ew[e]));
    }
}

// deg = 1 + sum(w) over bucket (sequential, no atomics); dinv = rsqrt(deg); cnt saved
__global__ void k_degdinv(const int* __restrict__ cursor, const uint2* __restrict__ packed,
                          int* __restrict__ cnt, float* __restrict__ dinv) {
    int i = blockIdx.x * blockDim.x + threadIdx.x;
    if (i < N_NODES) {
        int n = cursor[i] - i * CAP;
        cnt[i] = n;
        const uint2* seg = packed + (size_t)i * CAP;
        float d = 1.0f;
        for (int k = 0; k < n; ++k) d += __uint_as_float(seg[k].y);
        dinv[i] = rsqrtf(d);   // d >= 1 always
    }
}

// ---------------- prep: W1 -> frag-ready permuted bf16 + cursor init (fused) ----------
// w1p index: (((kk*4 + g)*128 + cc)*8 + j); B-frag elem j of lane group g covers
// k = kk*32 + g*4 + (j&3) + 16*(j>>2), column cc.

__global__ void k_prep(const float* __restrict__ W1, __bf16* __restrict__ w1p,
                       int* __restrict__ cursor) {
    int gidx = blockIdx.x * blockDim.x + threadIdx.x;
    if (gidx < F_IN * HID) {
        int k  = gidx >> 7;
        int cc = gidx & (HID - 1);
        int kk = k >> 5;
        int r  = k & 31;
        int g  = (r & 15) >> 2;
        int j  = (r & 3) + ((r >> 4) << 2);
        w1p[((((size_t)kk * 4 + g) * 128 + cc) << 3) + j] = (__bf16)W1[gidx];
    }
    if (gidx < N_NODES) cursor[gidx] = gidx * CAP;
}

// ---------------- layer 1 GEMM (MFMA bf16): hb = bf16(x @ W1) ----------------
// Barrier-free, LDS-free. 32x128 block tile, 4 waves 2x2, wave = 16x64 (1x4 frags).
// HAND-UNROLLED 16-step K-loop with NAMED register buffers (no arrays, no lambdas,
// no runtime indices -> nothing can be scratch-allocated or re-rolled; rule #20).
// Depth-2 prefetch over 3 named sets; fp32->bf16 cvt at CONSUME time only, so a
// set's loads have no dependent VALU until 2 steps later (counted vmcnt waits).
// __launch_bounds__(256,4): VGPR cap 128 (pipeline needs ~100).

__global__ __launch_bounds__(256, 4) void k_gemm1_mfma(const float* __restrict__ x,
                                                       const __bf16* __restrict__ w1p,
                                                       __bf16* __restrict__ hb) {
    const int tid  = threadIdx.x;
    const int lane = tid & 63;
    const int wid  = tid >> 6;
    const int wm   = wid >> 1;            // row block of 16
    const int wn   = wid & 1;             // col block of 64
    const int r0   = blockIdx.x * BM;
    const int g    = lane >> 4;           // k-group 0..3
    const int l15  = lane & 15;

    int rowi = r0 + wm * 16 + l15;
    if (rowi >= N_NODES) rowi = N_NODES - 1;   // clamp -> unconditional loads
    const float* px = x + (size_t)rowi * F_IN + g * 4;
    const __bf16* pb = w1p + (((size_t)g * 128) + wn * 64 + l15) * 8;  // + kk*4096

    f32x4 acc0 = {}, acc1 = {}, acc2 = {}, acc3 = {};
    float4 a0lo, a0hi, a1lo, a1hi, a2lo, a2hi;
    bf16x8 b0_0, b0_1, b0_2, b0_3;
    bf16x8 b1_0, b1_1, b1_2, b1_3;
    bf16x8 b2_0, b2_1, b2_2, b2_3;

#define LDA(kk, s) { a##s##lo = *(const float4*)(px + (kk) * 32); \
                     a##s##hi = *(const float4*)(px + (kk) * 32 + 16); }
#define LDB(kk, s) { const __bf16* bp = pb + (size_t)(kk) * 4096; \
                     b##s##_0 = *(const bf16x8*)(bp); \
                     b##s##_1 = *(const bf16x8*)(bp + 128); \
                     b##s##_2 = *(const bf16x8*)(bp + 256); \
                     b##s##_3 = *(const bf16x8*)(bp + 384); }
#define STEP(s) { union { __bf16 h[8]; bf16x8 v; } u; \
    u.h[0] = (__bf16)a##s##lo.x; u.h[1] = (__bf16)a##s##lo.y; \
    u.h[2] = (__bf16)a##s##lo.z; u.h[3] = (__bf16)a##s##lo.w; \
    u.h[4] = (__bf16)a##s##hi.x; u.h[5] = (__bf16)a##s##hi.y; \
    u.h[6] = (__bf16)a##s##hi.z; u.h[7] = (__bf16)a##s##hi.w; \
    acc0 = __builtin_amdgcn_mfma_f32_16x16x32_bf16(u.v, b##s##_0, acc0, 0, 0, 0); \
    acc1 = __builtin_amdgcn_mfma_f32_16x16x32_bf16(u.v, b##s##_1, acc1, 0, 0, 0); \
    acc2 = __builtin_amdgcn_mfma_f32_16x16x32_bf16(u.v, b##s##_2, acc2, 0, 0, 0); \
    acc3 = __builtin_amdgcn_mfma_f32_16x16x32_bf16(u.v, b##s##_3, acc3, 0, 0, 0); }

    LDA(0, 0)  LDB(0, 0)
    LDA(1, 1)  LDB(1, 1)
    LDA(2, 2)  LDB(2, 2)   STEP(0)
    LDA(3, 0)  LDB(3, 0)   STEP(1)
    LDA(4, 1)  LDB(4, 1)   STEP(2)
    LDA(5, 2)  LDB(5, 2)   STEP(0)
    LDA(6, 0)  LDB(6, 0)   STEP(1)
    LDA(7, 1)  LDB(7, 1)   STEP(2)
    LDA(8, 2)  LDB(8, 2)   STEP(0)
    LDA(9, 0)  LDB(9, 0)   STEP(1)
    LDA(10, 1) LDB(10, 1)  STEP(2)
    LDA(11, 2) LDB(11, 2)  STEP(0)
    LDA(12, 0) LDB(12, 0)  STEP(1)
    LDA(13, 1) LDB(13, 1)  STEP(2)
    LDA(14, 2) LDB(14, 2)  STEP(0)
    LDA(15, 0) LDB(15, 0)  STEP(1)
    STEP(2)
    STEP(0)
#undef LDA
#undef LDB
#undef STEP

    // epilogue: C/D col=lane&15, row=(lane>>4)*4+reg
    const int rb = r0 + wm * 16 + (g << 2);
#pragma unroll
    for (int rr = 0; rr < 4; ++rr) {
        int gr = rb + rr;
        if (gr < N_NODES) {
            __bf16* ho = hb + (size_t)gr * HID + wn * 64 + l15;
            ho[0]  = (__bf16)acc0[rr];
            ho[16] = (__bf16)acc1[rr];
            ho[32] = (__bf16)acc2[rr];
            ho[48] = (__bf16)acc3[rr];
        }
    }
}

// ---------------- layer 1 aggregation: 1 wave per node, bf16x2 packed, on-the-fly norm --

__device__ inline float blo(unsigned v) { union { unsigned u; float f; } c; c.u = v << 16; return c.f; }
__device__ inline float bhi(unsigned v) { union { unsigned u; float f; } c; c.u = v & 0xffff0000u; return c.f; }

__global__ __launch_bounds__(128) void k_agg1(const uint2* __restrict__ packed,
                                              const int* __restrict__ cnt,
                                              const __bf16* __restrict__ hb,
                                              const float* __restrict__ dinv,
                                              const float* __restrict__ b1,
                                              float* __restrict__ h1) {
    __shared__ int   sr[2][64];
    __shared__ float sn[2][64];
    const int w    = threadIdx.x >> 6;
    const int lane = threadIdx.x & 63;
    const int c    = blockIdx.x * 2 + w;
    const unsigned* hbu = (const unsigned*)hb;

    float dic = dinv[c];
    unsigned sv = hbu[((size_t)c << 6) + lane];
    float a0 = dic * dic * blo(sv);
    float a1 = dic * dic * bhi(sv);
    int n = cnt[c];
    const uint2* seg = packed + (size_t)c * CAP;
    for (int base = 0; base < n; base += 64) {
        int m = n - base; if (m > 64) m = 64;
        if (lane < m) {                       // wave-synchronous, no barrier
            uint2 pv = seg[base + lane];
            sr[w][lane] = (int)pv.x;
            sn[w][lane] = __uint_as_float(pv.y) * dinv[pv.x] * dic;
        }
        for (int t = 0; t < m; ++t) {
            float nm = sn[w][t];
            unsigned v = hbu[((size_t)sr[w][t] << 6) + lane];
            a0 = fmaf(nm, blo(v), a0);
            a1 = fmaf(nm, bhi(v), a1);
        }
    }
    float2 bb = *(const float2*)(b1 + 2 * lane);
    a0 += bb.x; a1 += bb.y;
    float2 o2;
    o2.x = a0 > 0.f ? a0 : 0.f;
    o2.y = a1 > 0.f ? a1 : 0.f;
    *(float2*)(h1 + ((size_t)c << 7) + 2 * lane) = o2;
}

// ---------------- layer 2 GEMM: h2 = h1 @ W2  (50000x128 @ 128x20) ----------------

__global__ __launch_bounds__(256) void k_gemm2(const float* __restrict__ h1,
                                               const float* __restrict__ W2,
                                               float* __restrict__ h2) {
    int g = blockIdx.x * blockDim.x + threadIdx.x;
    int i = g >> 5;
    int j = g & 31;
    if (i >= N_NODES || j >= OUT_F) return;
    float acc = 0.f;
    const float* hr = h1 + (size_t)i * HID;
    for (int k = 0; k < HID; ++k) acc = fmaf(hr[k], W2[k * OUT_F + j], acc);
    h2[(size_t)i * OUT_F + j] = acc;
}

// ---------------- layer 2 aggregation (on-the-fly norm) ----------------

__global__ __launch_bounds__(256) void k_agg2(const uint2* __restrict__ packed,
                                              const int* __restrict__ cnt,
                                              const float* __restrict__ h2,
                                              const float* __restrict__ dinv,
                                              const float* __restrict__ b2,
                                              float* __restrict__ out) {
    int g = blockIdx.x * blockDim.x + threadIdx.x;
    int c = g >> 5;
    int j = g & 31;
    if (c >= N_NODES || j >= OUT_F) return;
    float dic = dinv[c];
    float acc = dic * dic * h2[(size_t)c * OUT_F + j] + b2[j];
    int n = cnt[c];
    const uint2* seg = packed + (size_t)c * CAP;
    for (int k = 0; k < n; ++k) {
        uint2 pv = seg[k];                    // broadcast across lanes
        float nm = __uint_as_float(pv.y) * dinv[pv.x] * dic;
        acc = fmaf(nm, h2[(size_t)pv.x * OUT_F + j], acc);
    }
    out[(size_t)c * OUT_F + j] = acc;
}

// ---------------- launch ----------------

extern "C" void kernel_launch(void* const* d_in, const int* in_sizes, int n_in,
                              void* d_out, int out_size, void* d_ws, size_t ws_size,
                              hipStream_t stream) {
    const float* x  = (const float*)d_in[0];
    const int*   ei = (const int*)d_in[1];       // [2][E]
    const float* ew = (const float*)d_in[2];
    const float* W1 = (const float*)d_in[3];
    const float* b1 = (const float*)d_in[4];
    const float* W2 = (const float*)d_in[5];
    const float* b2 = (const float*)d_in[6];
    float* out = (float*)d_out;

    const int* row = ei;
    const int* col = ei + N_EDGES;

    char* p = (char*)d_ws;
    float* dinv   = (float*)p;  p += (size_t)N_NODES * 4;
    float* h1     = (float*)p;  p += (size_t)N_NODES * HID * 4;
    float* h2     = (float*)p;  p += (size_t)N_NODES * OUT_F * 4;
    __bf16* hb    = (__bf16*)p; p += (size_t)N_NODES * HID * 2;
    __bf16* w1p   = (__bf16*)p; p += (size_t)F_IN * HID * 2;
    int* cursor   = (int*)p;    p += (size_t)N_NODES * 4;
    int* cnt      = (int*)p;    p += (size_t)N_NODES * 4;
    uint2* packed = (uint2*)p;  p += (size_t)N_NODES * CAP * 8;

    // prep (W1 permute + cursor init), then CSR build: one atomic pass into buckets
    k_prep<<<(F_IN * HID + 255) / 256, 256, 0, stream>>>(W1, w1p, cursor);
    k_fillb<<<(N_EDGES + 255) / 256, 256, 0, stream>>>(row, col, ew, cursor, packed);
    k_degdinv<<<(N_NODES + 255) / 256, 256, 0, stream>>>(cursor, packed, cnt, dinv);

    // layer 1
    k_gemm1_mfma<<<(N_NODES + BM - 1) / BM, 256, 0, stream>>>(x, w1p, hb);
    k_agg1<<<N_NODES / 2, 128, 0, stream>>>(packed, cnt, hb, dinv, b1, h1);

    // layer 2
    k_gemm2<<<(N_NODES * 32 + 255) / 256, 256, 0, stream>>>(h1, W2, h2);
    k_agg2<<<(N_NODES * 32 + 255) / 256, 256, 0, stream>>>(packed, cnt, h2, dinv, b2, out);
}

// Round 11
// 222.320 us; speedup vs baseline: 1.0460x; 1.0423x over previous
//
#include <hip/hip_runtime.h>

#define N_NODES 50000
#define N_EDGES 800000
#define F_IN    512
#define HID     128
#define OUT_F   20
#define CAP     48           // max in-degree capacity (mean 16, 8 sigma headroom)

#define BM  32

typedef __bf16 bf16x8 __attribute__((ext_vector_type(8)));
typedef float  f32x4  __attribute__((ext_vector_type(4)));

// ---------------- CSR-by-destination via fixed-capacity buckets ----------------

// one atomic per edge; payload packed into a single 8B store
__global__ void k_fillb(const int* __restrict__ row, const int* __restrict__ col,
                        const float* __restrict__ ew, int* __restrict__ cursor,
                        uint2* __restrict__ packed) {
    int e = blockIdx.x * blockDim.x + threadIdx.x;
    if (e < N_EDGES) {
        int c = col[e];
        int pos = atomicAdd(&cursor[c], 1);
        packed[pos] = make_uint2((unsigned)row[e], __float_as_uint(ew[e]));
    }
}

// deg = 1 + sum(w) over bucket (sequential, no atomics); dinv = rsqrt(deg); cnt saved
__global__ void k_degdinv(const int* __restrict__ cursor, const uint2* __restrict__ packed,
                          int* __restrict__ cnt, float* __restrict__ dinv) {
    int i = blockIdx.x * blockDim.x + threadIdx.x;
    if (i < N_NODES) {
        int n = cursor[i] - i * CAP;
        cnt[i] = n;
        const uint2* seg = packed + (size_t)i * CAP;
        float d = 1.0f;
        for (int k = 0; k < n; ++k) d += __uint_as_float(seg[k].y);
        dinv[i] = rsqrtf(d);   // d >= 1 always
    }
}

// ---------------- prep: W1 -> frag-ready permuted bf16 + cursor init (fused) ----------
// w1p index: (((kk*4 + g)*128 + cc)*8 + j); B-frag elem j of lane group g covers
// k = kk*32 + g*4 + (j&3) + 16*(j>>2), column cc.

__global__ void k_prep(const float* __restrict__ W1, __bf16* __restrict__ w1p,
                       int* __restrict__ cursor) {
    int gidx = blockIdx.x * blockDim.x + threadIdx.x;
    if (gidx < F_IN * HID) {
        int k  = gidx >> 7;
        int cc = gidx & (HID - 1);
        int kk = k >> 5;
        int r  = k & 31;
        int g  = (r & 15) >> 2;
        int j  = (r & 3) + ((r >> 4) << 2);
        w1p[((((size_t)kk * 4 + g) * 128 + cc) << 3) + j] = (__bf16)W1[gidx];
    }
    if (gidx < N_NODES) cursor[gidx] = gidx * CAP;
}

// ---------------- layer 1 GEMM (MFMA bf16): hb = bf16(x @ W1) ----------------
// Barrier-free, LDS-free. 32x128 block tile, 4 waves 2x2, wave = 16x64 (1x4 frags).
// Hand-unrolled 16-step K-loop, named buffers, depth-2 prefetch over 3 sets, and
// __builtin_amdgcn_sched_barrier(0) pinning: the scheduler may NOT sink the
// prefetch loads past the fence into their consuming STEP (this sinking is what
// collapsed r8-r10 to VGPR=32 and a serial just-in-time schedule). cvt at consume.
// __launch_bounds__(256,4): VGPR cap 128 (pipeline needs ~100).

#define SB() __builtin_amdgcn_sched_barrier(0)

__global__ __launch_bounds__(256, 4) void k_gemm1_mfma(const float* __restrict__ x,
                                                       const __bf16* __restrict__ w1p,
                                                       __bf16* __restrict__ hb) {
    const int tid  = threadIdx.x;
    const int lane = tid & 63;
    const int wid  = tid >> 6;
    const int wm   = wid >> 1;            // row block of 16
    const int wn   = wid & 1;             // col block of 64
    const int r0   = blockIdx.x * BM;
    const int g    = lane >> 4;           // k-group 0..3
    const int l15  = lane & 15;

    int rowi = r0 + wm * 16 + l15;
    if (rowi >= N_NODES) rowi = N_NODES - 1;   // clamp -> unconditional loads
    const float* px = x + (size_t)rowi * F_IN + g * 4;
    const __bf16* pb = w1p + (((size_t)g * 128) + wn * 64 + l15) * 8;  // + kk*4096

    f32x4 acc0 = {}, acc1 = {}, acc2 = {}, acc3 = {};
    float4 a0lo, a0hi, a1lo, a1hi, a2lo, a2hi;
    bf16x8 b0_0, b0_1, b0_2, b0_3;
    bf16x8 b1_0, b1_1, b1_2, b1_3;
    bf16x8 b2_0, b2_1, b2_2, b2_3;

#define LDA(kk, s) { a##s##lo = *(const float4*)(px + (kk) * 32); \
                     a##s##hi = *(const float4*)(px + (kk) * 32 + 16); }
#define LDB(kk, s) { const __bf16* bp = pb + (size_t)(kk) * 4096; \
                     b##s##_0 = *(const bf16x8*)(bp); \
                     b##s##_1 = *(const bf16x8*)(bp + 128); \
                     b##s##_2 = *(const bf16x8*)(bp + 256); \
                     b##s##_3 = *(const bf16x8*)(bp + 384); }
#define STEP(s) { union { __bf16 h[8]; bf16x8 v; } u; \
    u.h[0] = (__bf16)a##s##lo.x; u.h[1] = (__bf16)a##s##lo.y; \
    u.h[2] = (__bf16)a##s##lo.z; u.h[3] = (__bf16)a##s##lo.w; \
    u.h[4] = (__bf16)a##s##hi.x; u.h[5] = (__bf16)a##s##hi.y; \
    u.h[6] = (__bf16)a##s##hi.z; u.h[7] = (__bf16)a##s##hi.w; \
    acc0 = __builtin_amdgcn_mfma_f32_16x16x32_bf16(u.v, b##s##_0, acc0, 0, 0, 0); \
    acc1 = __builtin_amdgcn_mfma_f32_16x16x32_bf16(u.v, b##s##_1, acc1, 0, 0, 0); \
    acc2 = __builtin_amdgcn_mfma_f32_16x16x32_bf16(u.v, b##s##_2, acc2, 0, 0, 0); \
    acc3 = __builtin_amdgcn_mfma_f32_16x16x32_bf16(u.v, b##s##_3, acc3, 0, 0, 0); }

    LDA(0, 0)  LDB(0, 0)
    LDA(1, 1)  LDB(1, 1)   SB();
    LDA(2, 2)  LDB(2, 2)   SB();  STEP(0)  SB();
    LDA(3, 0)  LDB(3, 0)   SB();  STEP(1)  SB();
    LDA(4, 1)  LDB(4, 1)   SB();  STEP(2)  SB();
    LDA(5, 2)  LDB(5, 2)   SB();  STEP(0)  SB();
    LDA(6, 0)  LDB(6, 0)   SB();  STEP(1)  SB();
    LDA(7, 1)  LDB(7, 1)   SB();  STEP(2)  SB();
    LDA(8, 2)  LDB(8, 2)   SB();  STEP(0)  SB();
    LDA(9, 0)  LDB(9, 0)   SB();  STEP(1)  SB();
    LDA(10, 1) LDB(10, 1)  SB();  STEP(2)  SB();
    LDA(11, 2) LDB(11, 2)  SB();  STEP(0)  SB();
    LDA(12, 0) LDB(12, 0)  SB();  STEP(1)  SB();
    LDA(13, 1) LDB(13, 1)  SB();  STEP(2)  SB();
    LDA(14, 2) LDB(14, 2)  SB();  STEP(0)  SB();
    LDA(15, 0) LDB(15, 0)  SB();  STEP(1)  SB();
    STEP(2)
    STEP(0)
#undef LDA
#undef LDB
#undef STEP

    // epilogue: C/D col=lane&15, row=(lane>>4)*4+reg
    const int rb = r0 + wm * 16 + (g << 2);
#pragma unroll
    for (int rr = 0; rr < 4; ++rr) {
        int gr = rb + rr;
        if (gr < N_NODES) {
            __bf16* ho = hb + (size_t)gr * HID + wn * 64 + l15;
            ho[0]  = (__bf16)acc0[rr];
            ho[16] = (__bf16)acc1[rr];
            ho[32] = (__bf16)acc2[rr];
            ho[48] = (__bf16)acc3[rr];
        }
    }
}

// ---------------- layer 1 aggregation: 1 wave per node, bf16x2 packed, on-the-fly norm --
// h1 now stored as packed bf16x2 (halves write traffic; gemm2 read halves too).

__device__ inline float blo(unsigned v) { union { unsigned u; float f; } c; c.u = v << 16; return c.f; }
__device__ inline float bhi(unsigned v) { union { unsigned u; float f; } c; c.u = v & 0xffff0000u; return c.f; }

__global__ __launch_bounds__(128) void k_agg1(const uint2* __restrict__ packed,
                                              const int* __restrict__ cnt,
                                              const __bf16* __restrict__ hb,
                                              const float* __restrict__ dinv,
                                              const float* __restrict__ b1,
                                              unsigned* __restrict__ h1b) {
    __shared__ int   sr[2][64];
    __shared__ float sn[2][64];
    const int w    = threadIdx.x >> 6;
    const int lane = threadIdx.x & 63;
    const int c    = blockIdx.x * 2 + w;
    const unsigned* hbu = (const unsigned*)hb;

    float dic = dinv[c];
    unsigned sv = hbu[((size_t)c << 6) + lane];
    float a0 = dic * dic * blo(sv);
    float a1 = dic * dic * bhi(sv);
    int n = cnt[c];
    const uint2* seg = packed + (size_t)c * CAP;
    for (int base = 0; base < n; base += 64) {
        int m = n - base; if (m > 64) m = 64;
        if (lane < m) {                       // wave-synchronous, no barrier
            uint2 pv = seg[base + lane];
            sr[w][lane] = (int)pv.x;
            sn[w][lane] = __uint_as_float(pv.y) * dinv[pv.x] * dic;
        }
        for (int t = 0; t < m; ++t) {
            float nm = sn[w][t];
            unsigned v = hbu[((size_t)sr[w][t] << 6) + lane];
            a0 = fmaf(nm, blo(v), a0);
            a1 = fmaf(nm, bhi(v), a1);
        }
    }
    float2 bb = *(const float2*)(b1 + 2 * lane);
    a0 += bb.x; a1 += bb.y;
    union { __bf16 h[2]; unsigned u; } o;
    o.h[0] = (__bf16)(a0 > 0.f ? a0 : 0.f);
    o.h[1] = (__bf16)(a1 > 0.f ? a1 : 0.f);
    h1b[((size_t)c << 6) + lane] = o.u;
}

// ---------------- layer 2 GEMM: h2 = h1 @ W2  (50000x128 @ 128x20), h1 in bf16 ------

__global__ __launch_bounds__(256) void k_gemm2(const unsigned* __restrict__ h1b,
                                               const float* __restrict__ W2,
                                               float* __restrict__ h2) {
    int g = blockIdx.x * blockDim.x + threadIdx.x;
    int i = g >> 5;
    int j = g & 31;
    if (i >= N_NODES || j >= OUT_F) return;
    float acc = 0.f;
    const unsigned* hr = h1b + ((size_t)i << 6);
    for (int k2 = 0; k2 < 64; ++k2) {
        unsigned v = hr[k2];                  // 2 bf16 (k=2*k2, 2*k2+1)
        acc = fmaf(blo(v), W2[(2 * k2) * OUT_F + j],
              fmaf(bhi(v), W2[(2 * k2 + 1) * OUT_F + j], acc));
    }
    h2[(size_t)i * OUT_F + j] = acc;
}

// ---------------- layer 2 aggregation (on-the-fly norm) ----------------

__global__ __launch_bounds__(256) void k_agg2(const uint2* __restrict__ packed,
                                              const int* __restrict__ cnt,
                                              const float* __restrict__ h2,
                                              const float* __restrict__ dinv,
                                              const float* __restrict__ b2,
                                              float* __restrict__ out) {
    int g = blockIdx.x * blockDim.x + threadIdx.x;
    int c = g >> 5;
    int j = g & 31;
    if (c >= N_NODES || j >= OUT_F) return;
    float dic = dinv[c];
    float acc = dic * dic * h2[(size_t)c * OUT_F + j] + b2[j];
    int n = cnt[c];
    const uint2* seg = packed + (size_t)c * CAP;
    for (int k = 0; k < n; ++k) {
        uint2 pv = seg[k];                    // broadcast across lanes
        float nm = __uint_as_float(pv.y) * dinv[pv.x] * dic;
        acc = fmaf(nm, h2[(size_t)pv.x * OUT_F + j], acc);
    }
    out[(size_t)c * OUT_F + j] = acc;
}

// ---------------- launch ----------------

extern "C" void kernel_launch(void* const* d_in, const int* in_sizes, int n_in,
                              void* d_out, int out_size, void* d_ws, size_t ws_size,
                              hipStream_t stream) {
    const float* x  = (const float*)d_in[0];
    const int*   ei = (const int*)d_in[1];       // [2][E]
    const float* ew = (const float*)d_in[2];
    const float* W1 = (const float*)d_in[3];
    const float* b1 = (const float*)d_in[4];
    const float* W2 = (const float*)d_in[5];
    const float* b2 = (const float*)d_in[6];
    float* out = (float*)d_out;

    const int* row = ei;
    const int* col = ei + N_EDGES;

    char* p = (char*)d_ws;
    float* dinv    = (float*)p;    p += (size_t)N_NODES * 4;
    unsigned* h1b  = (unsigned*)p; p += (size_t)N_NODES * 64 * 4;   // bf16x2 packed
    float* h2      = (float*)p;    p += (size_t)N_NODES * OUT_F * 4;
    __bf16* hb     = (__bf16*)p;   p += (size_t)N_NODES * HID * 2;
    __bf16* w1p    = (__bf16*)p;   p += (size_t)F_IN * HID * 2;
    int* cursor    = (int*)p;      p += (size_t)N_NODES * 4;
    int* cnt       = (int*)p;      p += (size_t)N_NODES * 4;
    uint2* packed  = (uint2*)p;    p += (size_t)N_NODES * CAP * 8;

    // prep (W1 permute + cursor init), then CSR build: one atomic pass into buckets
    k_prep<<<(F_IN * HID + 255) / 256, 256, 0, stream>>>(W1, w1p, cursor);
    k_fillb<<<(N_EDGES + 255) / 256, 256, 0, stream>>>(row, col, ew, cursor, packed);
    k_degdinv<<<(N_NODES + 255) / 256, 256, 0, stream>>>(cursor, packed, cnt, dinv);

    // layer 1
    k_gemm1_mfma<<<(N_NODES + BM - 1) / BM, 256, 0, stream>>>(x, w1p, hb);
    k_agg1<<<N_NODES / 2, 128, 0, stream>>>(packed, cnt, hb, dinv, b1, h1b);

    // layer 2
    k_gemm2<<<(N_NODES * 32 + 255) / 256, 256, 0, stream>>>(h1b, W2, h2);
    k_agg2<<<(N_NODES * 32 + 255) / 256, 256, 0, stream>>>(packed, cnt, h2, dinv, b2, out);
}

// Round 12
// 204.367 us; speedup vs baseline: 1.1379x; 1.0878x over previous
//
#include <hip/hip_runtime.h>

#define N_NODES 50000
#define N_EDGES 800000
#define F_IN    512
#define HID     128
#define OUT_F   20
#define CAP     48           // max in-degree capacity (mean 16, 8 sigma headroom)

#define BM  32

typedef __bf16 bf16x8 __attribute__((ext_vector_type(8)));
typedef float  f32x4  __attribute__((ext_vector_type(4)));

// ---------------- CSR-by-destination via fixed-capacity buckets ----------------

// one atomic per edge; payload packed into a single 8B store
__global__ void k_fillb(const int* __restrict__ row, const int* __restrict__ col,
                        const float* __restrict__ ew, int* __restrict__ cursor,
                        uint2* __restrict__ packed) {
    int e = blockIdx.x * blockDim.x + threadIdx.x;
    if (e < N_EDGES) {
        int c = col[e];
        int pos = atomicAdd(&cursor[c], 1);
        packed[pos] = make_uint2((unsigned)row[e], __float_as_uint(ew[e]));
    }
}

// deg = 1 + sum(w) over bucket (sequential, no atomics); dinv = rsqrt(deg); cnt saved
__global__ void k_degdinv(const int* __restrict__ cursor, const uint2* __restrict__ packed,
                          int* __restrict__ cnt, float* __restrict__ dinv) {
    int i = blockIdx.x * blockDim.x + threadIdx.x;
    if (i < N_NODES) {
        int n = cursor[i] - i * CAP;
        cnt[i] = n;
        const uint2* seg = packed + (size_t)i * CAP;
        float d = 1.0f;
        for (int k = 0; k < n; ++k) d += __uint_as_float(seg[k].y);
        dinv[i] = rsqrtf(d);   // d >= 1 always
    }
}

// ---------------- prep: W1 -> frag-ready permuted bf16 + cursor init (fused) ----------
// w1p index: (((kk*4 + g)*128 + cc)*8 + j); B-frag elem j of lane group g covers
// k = kk*32 + g*4 + (j&3) + 16*(j>>2), column cc.

__global__ void k_prep(const float* __restrict__ W1, __bf16* __restrict__ w1p,
                       int* __restrict__ cursor) {
    int gidx = blockIdx.x * blockDim.x + threadIdx.x;
    if (gidx < F_IN * HID) {
        int k  = gidx >> 7;
        int cc = gidx & (HID - 1);
        int kk = k >> 5;
        int r  = k & 31;
        int g  = (r & 15) >> 2;
        int j  = (r & 3) + ((r >> 4) << 2);
        w1p[((((size_t)kk * 4 + g) * 128 + cc) << 3) + j] = (__bf16)W1[gidx];
    }
    if (gidx < N_NODES) cursor[gidx] = gidx * CAP;
}

// ---------------- layer 1 GEMM (MFMA bf16): hb = bf16(x @ W1) ----------------
// A-pipeline via global_load_lds (r8-r11 lesson: VGPR-destined prefetch always
// collapses to just-in-time; global_load_lds writes no VGPR -> cannot collapse).
// BM=32, BK=128 f32: As[2][32*128] = 32 KB LDS -> ~5 blocks/CU, 1563 blocks.
// 4 K-tiles; stage(t+1) issued BEFORE compute(t); one barrier per tile (4 total).
// A staged as RAW fp32 (cvt at consume from LDS). Source pre-swizzled slot^(row&7)
// per 16B chunk (both-sides rule); consume ds_read_b128 is bank-uniform.
// B: per-kk frag-register loads from L2-hot w1p (1 KB/wave/tile, hidden by TLP).

__global__ __launch_bounds__(256) void k_gemm1_mfma(const float* __restrict__ x,
                                                    const __bf16* __restrict__ w1p,
                                                    __bf16* __restrict__ hb) {
    __shared__ float As[2][BM * 128];     // 16 KB per buffer
    const int tid  = threadIdx.x;
    const int lane = tid & 63;
    const int wid  = tid >> 6;
    const int wm   = wid >> 1;            // row block of 16
    const int wn   = wid & 1;             // col block of 64
    const int r0   = blockIdx.x * BM;
    const int g    = lane >> 4;           // k-group 0..3
    const int l15  = lane & 15;

    const __bf16* pb = w1p + (((size_t)g * 128) + wn * 64 + l15) * 8;  // + kkg*4096

    f32x4 acc0 = {}, acc1 = {}, acc2 = {}, acc3 = {};

    // stage one BK=128 tile (1024 x 16B chunks; 4 global_load_lds per thread)
    auto stage = [&](int buf, int k0) {
#pragma unroll
        for (int i = 0; i < 4; ++i) {
            int cb = wid * 64 + i * 256;          // wave-uniform chunk base
            int c  = cb + lane;                    // chunk id 0..1023
            int rowc = c >> 5;                     // row 0..31 (32 chunks/row)
            int s    = c & 31;                     // 16B slot in row
            int gr = r0 + rowc;
            if (gr >= N_NODES) gr = N_NODES - 1;   // clamp (stores guarded later)
            const float* src = x + (size_t)gr * F_IN + k0 + ((s ^ (rowc & 7)) << 2);
            __builtin_amdgcn_global_load_lds(
                (const __attribute__((address_space(1))) void*)src,
                (__attribute__((address_space(3))) void*)(&As[buf][(size_t)cb * 4]),
                16, 0, 0);
        }
    };

    const int rowm = wm * 16 + l15;
    const int rbase = rowm * 128;
    const int rx = rowm & 7;

    stage(0, 0);
    __syncthreads();                      // drains vmcnt: tile 0 ready

#pragma unroll
    for (int t = 0; t < 4; ++t) {
        const int buf = t & 1;
        if (t < 3) stage(buf ^ 1, (t + 1) * 128);   // loads in flight across compute
#pragma unroll
        for (int kk = 0; kk < 4; ++kk) {
            // A frag: two b128 reads from swizzled LDS, cvt at consume
            int slo = ((kk * 8 + g)     ^ rx) << 2;
            int shi = ((kk * 8 + g + 4) ^ rx) << 2;
            f32x4 lo = *(const f32x4*)&As[buf][rbase + slo];
            f32x4 hi = *(const f32x4*)&As[buf][rbase + shi];
            union { __bf16 h[8]; bf16x8 v; } u;
            u.h[0] = (__bf16)lo[0]; u.h[1] = (__bf16)lo[1];
            u.h[2] = (__bf16)lo[2]; u.h[3] = (__bf16)lo[3];
            u.h[4] = (__bf16)hi[0]; u.h[5] = (__bf16)hi[1];
            u.h[6] = (__bf16)hi[2]; u.h[7] = (__bf16)hi[3];
            // B frags (L2-hot)
            const __bf16* bp = pb + (size_t)(t * 4 + kk) * 4096;
            bf16x8 b0 = *(const bf16x8*)(bp);
            bf16x8 b1 = *(const bf16x8*)(bp + 128);
            bf16x8 b2 = *(const bf16x8*)(bp + 256);
            bf16x8 b3 = *(const bf16x8*)(bp + 384);
            acc0 = __builtin_amdgcn_mfma_f32_16x16x32_bf16(u.v, b0, acc0, 0, 0, 0);
            acc1 = __builtin_amdgcn_mfma_f32_16x16x32_bf16(u.v, b1, acc1, 0, 0, 0);
            acc2 = __builtin_amdgcn_mfma_f32_16x16x32_bf16(u.v, b2, acc2, 0, 0, 0);
            acc3 = __builtin_amdgcn_mfma_f32_16x16x32_bf16(u.v, b3, acc3, 0, 0, 0);
        }
        __syncthreads();                  // next tile staged + all waves done reading
    }

    // epilogue: C/D col=lane&15, row=(lane>>4)*4+reg
    const int rb = r0 + wm * 16 + (g << 2);
#pragma unroll
    for (int rr = 0; rr < 4; ++rr) {
        int gr = rb + rr;
        if (gr < N_NODES) {
            __bf16* ho = hb + (size_t)gr * HID + wn * 64 + l15;
            ho[0]  = (__bf16)acc0[rr];
            ho[16] = (__bf16)acc1[rr];
            ho[32] = (__bf16)acc2[rr];
            ho[48] = (__bf16)acc3[rr];
        }
    }
}

// ---------------- layer 1 aggregation: 1 wave per node, bf16x2 packed, on-the-fly norm --
// h1 stored as packed bf16x2 (halves write traffic; gemm2 read halves too).

__device__ inline float blo(unsigned v) { union { unsigned u; float f; } c; c.u = v << 16; return c.f; }
__device__ inline float bhi(unsigned v) { union { unsigned u; float f; } c; c.u = v & 0xffff0000u; return c.f; }

__global__ __launch_bounds__(128) void k_agg1(const uint2* __restrict__ packed,
                                              const int* __restrict__ cnt,
                                              const __bf16* __restrict__ hb,
                                              const float* __restrict__ dinv,
                                              const float* __restrict__ b1,
                                              unsigned* __restrict__ h1b) {
    __shared__ int   sr[2][64];
    __shared__ float sn[2][64];
    const int w    = threadIdx.x >> 6;
    const int lane = threadIdx.x & 63;
    const int c    = blockIdx.x * 2 + w;
    const unsigned* hbu = (const unsigned*)hb;

    float dic = dinv[c];
    unsigned sv = hbu[((size_t)c << 6) + lane];
    float a0 = dic * dic * blo(sv);
    float a1 = dic * dic * bhi(sv);
    int n = cnt[c];
    const uint2* seg = packed + (size_t)c * CAP;
    for (int base = 0; base < n; base += 64) {
        int m = n - base; if (m > 64) m = 64;
        if (lane < m) {                       // wave-synchronous, no barrier
            uint2 pv = seg[base + lane];
            sr[w][lane] = (int)pv.x;
            sn[w][lane] = __uint_as_float(pv.y) * dinv[pv.x] * dic;
        }
        for (int t = 0; t < m; ++t) {
            float nm = sn[w][t];
            unsigned v = hbu[((size_t)sr[w][t] << 6) + lane];
            a0 = fmaf(nm, blo(v), a0);
            a1 = fmaf(nm, bhi(v), a1);
        }
    }
    float2 bb = *(const float2*)(b1 + 2 * lane);
    a0 += bb.x; a1 += bb.y;
    union { __bf16 h[2]; unsigned u; } o;
    o.h[0] = (__bf16)(a0 > 0.f ? a0 : 0.f);
    o.h[1] = (__bf16)(a1 > 0.f ? a1 : 0.f);
    h1b[((size_t)c << 6) + lane] = o.u;
}

// ---------------- layer 2 GEMM: h2 = h1 @ W2  (50000x128 @ 128x20), h1 in bf16 ------

__global__ __launch_bounds__(256) void k_gemm2(const unsigned* __restrict__ h1b,
                                               const float* __restrict__ W2,
                                               float* __restrict__ h2) {
    int g = blockIdx.x * blockDim.x + threadIdx.x;
    int i = g >> 5;
    int j = g & 31;
    if (i >= N_NODES || j >= OUT_F) return;
    float acc = 0.f;
    const unsigned* hr = h1b + ((size_t)i << 6);
    for (int k2 = 0; k2 < 64; ++k2) {
        unsigned v = hr[k2];                  // 2 bf16 (k=2*k2, 2*k2+1)
        acc = fmaf(blo(v), W2[(2 * k2) * OUT_F + j],
              fmaf(bhi(v), W2[(2 * k2 + 1) * OUT_F + j], acc));
    }
    h2[(size_t)i * OUT_F + j] = acc;
}

// ---------------- layer 2 aggregation (on-the-fly norm) ----------------

__global__ __launch_bounds__(256) void k_agg2(const uint2* __restrict__ packed,
                                              const int* __restrict__ cnt,
                                              const float* __restrict__ h2,
                                              const float* __restrict__ dinv,
                                              const float* __restrict__ b2,
                                              float* __restrict__ out) {
    int g = blockIdx.x * blockDim.x + threadIdx.x;
    int c = g >> 5;
    int j = g & 31;
    if (c >= N_NODES || j >= OUT_F) return;
    float dic = dinv[c];
    float acc = dic * dic * h2[(size_t)c * OUT_F + j] + b2[j];
    int n = cnt[c];
    const uint2* seg = packed + (size_t)c * CAP;
    for (int k = 0; k < n; ++k) {
        uint2 pv = seg[k];                    // broadcast across lanes
        float nm = __uint_as_float(pv.y) * dinv[pv.x] * dic;
        acc = fmaf(nm, h2[(size_t)pv.x * OUT_F + j], acc);
    }
    out[(size_t)c * OUT_F + j] = acc;
}

// ---------------- launch ----------------

extern "C" void kernel_launch(void* const* d_in, const int* in_sizes, int n_in,
                              void* d_out, int out_size, void* d_ws, size_t ws_size,
                              hipStream_t stream) {
    const float* x  = (const float*)d_in[0];
    const int*   ei = (const int*)d_in[1];       // [2][E]
    const float* ew = (const float*)d_in[2];
    const float* W1 = (const float*)d_in[3];
    const float* b1 = (const float*)d_in[4];
    const float* W2 = (const float*)d_in[5];
    const float* b2 = (const float*)d_in[6];
    float* out = (float*)d_out;

    const int* row = ei;
    const int* col = ei + N_EDGES;

    char* p = (char*)d_ws;
    float* dinv    = (float*)p;    p += (size_t)N_NODES * 4;
    unsigned* h1b  = (unsigned*)p; p += (size_t)N_NODES * 64 * 4;   // bf16x2 packed
    float* h2      = (float*)p;    p += (size_t)N_NODES * OUT_F * 4;
    __bf16* hb     = (__bf16*)p;   p += (size_t)N_NODES * HID * 2;
    __bf16* w1p    = (__bf16*)p;   p += (size_t)F_IN * HID * 2;
    int* cursor    = (int*)p;      p += (size_t)N_NODES * 4;
    int* cnt       = (int*)p;      p += (size_t)N_NODES * 4;
    uint2* packed  = (uint2*)p;    p += (size_t)N_NODES * CAP * 8;

    // prep (W1 permute + cursor init), then CSR build: one atomic pass into buckets
    k_prep<<<(F_IN * HID + 255) / 256, 256, 0, stream>>>(W1, w1p, cursor);
    k_fillb<<<(N_EDGES + 255) / 256, 256, 0, stream>>>(row, col, ew, cursor, packed);
    k_degdinv<<<(N_NODES + 255) / 256, 256, 0, stream>>>(cursor, packed, cnt, dinv);

    // layer 1
    k_gemm1_mfma<<<(N_NODES + BM - 1) / BM, 256, 0, stream>>>(x, w1p, hb);
    k_agg1<<<N_NODES / 2, 128, 0, stream>>>(packed, cnt, hb, dinv, b1, h1b);

    // layer 2
    k_gemm2<<<(N_NODES * 32 + 255) / 256, 256, 0, stream>>>(h1b, W2, h2);
    k_agg2<<<(N_NODES * 32 + 255) / 256, 256, 0, stream>>>(packed, cnt, h2, dinv, b2, out);
}

// Round 13
// 190.516 us; speedup vs baseline: 1.2206x; 1.0727x over previous
//
#include <hip/hip_runtime.h>

#define N_NODES 50000
#define N_EDGES 800000
#define F_IN    512
#define HID     128
#define OUT_F   20
#define CAP     48           // max in-degree capacity (mean 16, 8 sigma headroom)

#define BM  32
#define GEMM_BLOCKS ((N_NODES + BM - 1) / BM)   // 1563 = 521*3
#define FB_BLOCKS   521
#define FAT_BLOCKS  (FB_BLOCKS * 4)             // 2084: bid&3==3 -> fillb, else gemm

typedef __bf16 bf16x8 __attribute__((ext_vector_type(8)));
typedef float  f32x4  __attribute__((ext_vector_type(4)));

// ---------------- prep: W1 -> frag-ready permuted bf16 + cursor init (fused) ----------
// w1p index: (((kk*4 + g)*128 + cc)*8 + j); B-frag elem j of lane group g covers
// k = kk*32 + g*4 + (j&3) + 16*(j>>2), column cc.

__global__ void k_prep(const float* __restrict__ W1, __bf16* __restrict__ w1p,
                       int* __restrict__ cursor) {
    int gidx = blockIdx.x * blockDim.x + threadIdx.x;
    if (gidx < F_IN * HID) {
        int k  = gidx >> 7;
        int cc = gidx & (HID - 1);
        int kk = k >> 5;
        int r  = k & 31;
        int g  = (r & 15) >> 2;
        int j  = (r & 3) + ((r >> 4) << 2);
        w1p[((((size_t)kk * 4 + g) * 128 + cc) << 3) + j] = (__bf16)W1[gidx];
    }
    if (gidx < N_NODES) cursor[gidx] = gidx * CAP;
}

// ---------------- FAT kernel: gemm1 (MFMA, LDS-pipelined) || fillb (atomic CSR) -------
// Both paths are the individually-profiled r12 kernels, merged 3:1 so the
// atomic-latency-bound fillb waves hide under gemm1's memory slots (complementary
// pipes: gemm1 = HBM+MFMA+LDS, fillb = atomic queue, ~0 VALU/BW).

__global__ __launch_bounds__(256) void k_fat(const float* __restrict__ x,
                                             const __bf16* __restrict__ w1p,
                                             __bf16* __restrict__ hb,
                                             const int* __restrict__ row,
                                             const int* __restrict__ col,
                                             const float* __restrict__ ew,
                                             int* __restrict__ cursor,
                                             uint2* __restrict__ packed) {
    __shared__ float As[2][BM * 128];     // 16 KB per buffer (gemm path only)
    const int tid = threadIdx.x;
    const int q   = blockIdx.x >> 2;
    const int r3  = blockIdx.x & 3;

    if (r3 == 3) {
        // ---------- fillb path: grid-stride, one atomic + one 8B store per edge ------
        for (int e = q * 256 + tid; e < N_EDGES; e += FB_BLOCKS * 256) {
            int c = col[e];
            int pos = atomicAdd(&cursor[c], 1);
            packed[pos] = make_uint2((unsigned)row[e], __float_as_uint(ew[e]));
        }
        return;
    }

    // ---------- gemm1 path ----------
    const int gemm_id = q * 3 + r3;       // 0..1562, each exactly once
    const int lane = tid & 63;
    const int wid  = tid >> 6;
    const int wm   = wid >> 1;            // row block of 16
    const int wn   = wid & 1;             // col block of 64
    const int r0   = gemm_id * BM;
    const int g    = lane >> 4;           // k-group 0..3
    const int l15  = lane & 15;

    const __bf16* pb = w1p + (((size_t)g * 128) + wn * 64 + l15) * 8;  // + kkg*4096

    f32x4 acc0 = {}, acc1 = {}, acc2 = {}, acc3 = {};

    // stage one BK=128 tile (1024 x 16B chunks; 4 global_load_lds per thread)
    auto stage = [&](int buf, int k0) {
#pragma unroll
        for (int i = 0; i < 4; ++i) {
            int cb = wid * 64 + i * 256;          // wave-uniform chunk base
            int c  = cb + lane;                    // chunk id 0..1023
            int rowc = c >> 5;                     // row 0..31 (32 chunks/row)
            int s    = c & 31;                     // 16B slot in row
            int gr = r0 + rowc;
            if (gr >= N_NODES) gr = N_NODES - 1;   // clamp (stores guarded later)
            const float* src = x + (size_t)gr * F_IN + k0 + ((s ^ (rowc & 7)) << 2);
            __builtin_amdgcn_global_load_lds(
                (const __attribute__((address_space(1))) void*)src,
                (__attribute__((address_space(3))) void*)(&As[buf][(size_t)cb * 4]),
                16, 0, 0);
        }
    };

    const int rowm = wm * 16 + l15;
    const int rbase = rowm * 128;
    const int rx = rowm & 7;

    stage(0, 0);
    __syncthreads();                      // drains vmcnt: tile 0 ready

#pragma unroll
    for (int t = 0; t < 4; ++t) {
        const int buf = t & 1;
        if (t < 3) stage(buf ^ 1, (t + 1) * 128);   // loads in flight across compute
#pragma unroll
        for (int kk = 0; kk < 4; ++kk) {
            // A frag: two b128 reads from swizzled LDS, cvt at consume
            int slo = ((kk * 8 + g)     ^ rx) << 2;
            int shi = ((kk * 8 + g + 4) ^ rx) << 2;
            f32x4 lo = *(const f32x4*)&As[buf][rbase + slo];
            f32x4 hi = *(const f32x4*)&As[buf][rbase + shi];
            union { __bf16 h[8]; bf16x8 v; } u;
            u.h[0] = (__bf16)lo[0]; u.h[1] = (__bf16)lo[1];
            u.h[2] = (__bf16)lo[2]; u.h[3] = (__bf16)lo[3];
            u.h[4] = (__bf16)hi[0]; u.h[5] = (__bf16)hi[1];
            u.h[6] = (__bf16)hi[2]; u.h[7] = (__bf16)hi[3];
            // B frags (L2-hot)
            const __bf16* bp = pb + (size_t)(t * 4 + kk) * 4096;
            bf16x8 b0 = *(const bf16x8*)(bp);
            bf16x8 b1 = *(const bf16x8*)(bp + 128);
            bf16x8 b2 = *(const bf16x8*)(bp + 256);
            bf16x8 b3 = *(const bf16x8*)(bp + 384);
            acc0 = __builtin_amdgcn_mfma_f32_16x16x32_bf16(u.v, b0, acc0, 0, 0, 0);
            acc1 = __builtin_amdgcn_mfma_f32_16x16x32_bf16(u.v, b1, acc1, 0, 0, 0);
            acc2 = __builtin_amdgcn_mfma_f32_16x16x32_bf16(u.v, b2, acc2, 0, 0, 0);
            acc3 = __builtin_amdgcn_mfma_f32_16x16x32_bf16(u.v, b3, acc3, 0, 0, 0);
        }
        __syncthreads();                  // next tile staged + all waves done reading
    }

    // epilogue: C/D col=lane&15, row=(lane>>4)*4+reg
    const int rb = r0 + wm * 16 + (g << 2);
#pragma unroll
    for (int rr = 0; rr < 4; ++rr) {
        int gr = rb + rr;
        if (gr < N_NODES) {
            __bf16* ho = hb + (size_t)gr * HID + wn * 64 + l15;
            ho[0]  = (__bf16)acc0[rr];
            ho[16] = (__bf16)acc1[rr];
            ho[32] = (__bf16)acc2[rr];
            ho[48] = (__bf16)acc3[rr];
        }
    }
}

// ---------------- deg/dinv from buckets (sequential, no atomics) ----------------

__global__ void k_degdinv(const int* __restrict__ cursor, const uint2* __restrict__ packed,
                          int* __restrict__ cnt, float* __restrict__ dinv) {
    int i = blockIdx.x * blockDim.x + threadIdx.x;
    if (i < N_NODES) {
        int n = cursor[i] - i * CAP;
        cnt[i] = n;
        const uint2* seg = packed + (size_t)i * CAP;
        float d = 1.0f;
        for (int k = 0; k < n; ++k) d += __uint_as_float(seg[k].y);
        dinv[i] = rsqrtf(d);   // d >= 1 always
    }
}

// ---------------- layer 1 aggregation: 1 wave per node, bf16x2 packed, on-the-fly norm --

__device__ inline float blo(unsigned v) { union { unsigned u; float f; } c; c.u = v << 16; return c.f; }
__device__ inline float bhi(unsigned v) { union { unsigned u; float f; } c; c.u = v & 0xffff0000u; return c.f; }

__global__ __launch_bounds__(128) void k_agg1(const uint2* __restrict__ packed,
                                              const int* __restrict__ cnt,
                                              const __bf16* __restrict__ hb,
                                              const float* __restrict__ dinv,
                                              const float* __restrict__ b1,
                                              unsigned* __restrict__ h1b) {
    __shared__ int   sr[2][64];
    __shared__ float sn[2][64];
    const int w    = threadIdx.x >> 6;
    const int lane = threadIdx.x & 63;
    const int c    = blockIdx.x * 2 + w;
    const unsigned* hbu = (const unsigned*)hb;

    float dic = dinv[c];
    unsigned sv = hbu[((size_t)c << 6) + lane];
    float a0 = dic * dic * blo(sv);
    float a1 = dic * dic * bhi(sv);
    int n = cnt[c];
    const uint2* seg = packed + (size_t)c * CAP;
    for (int base = 0; base < n; base += 64) {
        int m = n - base; if (m > 64) m = 64;
        if (lane < m) {                       // wave-synchronous, no barrier
            uint2 pv = seg[base + lane];
            sr[w][lane] = (int)pv.x;
            sn[w][lane] = __uint_as_float(pv.y) * dinv[pv.x] * dic;
        }
        for (int t = 0; t < m; ++t) {
            float nm = sn[w][t];
            unsigned v = hbu[((size_t)sr[w][t] << 6) + lane];
            a0 = fmaf(nm, blo(v), a0);
            a1 = fmaf(nm, bhi(v), a1);
        }
    }
    float2 bb = *(const float2*)(b1 + 2 * lane);
    a0 += bb.x; a1 += bb.y;
    union { __bf16 h[2]; unsigned u; } o;
    o.h[0] = (__bf16)(a0 > 0.f ? a0 : 0.f);
    o.h[1] = (__bf16)(a1 > 0.f ? a1 : 0.f);
    h1b[((size_t)c << 6) + lane] = o.u;
}

// ---------------- layer 2 GEMM: h2 = h1 @ W2  (50000x128 @ 128x20), h1 in bf16 ------

__global__ __launch_bounds__(256) void k_gemm2(const unsigned* __restrict__ h1b,
                                               const float* __restrict__ W2,
                                               float* __restrict__ h2) {
    int g = blockIdx.x * blockDim.x + threadIdx.x;
    int i = g >> 5;
    int j = g & 31;
    if (i >= N_NODES || j >= OUT_F) return;
    float acc = 0.f;
    const unsigned* hr = h1b + ((size_t)i << 6);
    for (int k2 = 0; k2 < 64; ++k2) {
        unsigned v = hr[k2];                  // 2 bf16 (k=2*k2, 2*k2+1)
        acc = fmaf(blo(v), W2[(2 * k2) * OUT_F + j],
              fmaf(bhi(v), W2[(2 * k2 + 1) * OUT_F + j], acc));
    }
    h2[(size_t)i * OUT_F + j] = acc;
}

// ---------------- layer 2 aggregation (on-the-fly norm) ----------------

__global__ __launch_bounds__(256) void k_agg2(const uint2* __restrict__ packed,
                                              const int* __restrict__ cnt,
                                              const float* __restrict__ h2,
                                              const float* __restrict__ dinv,
                                              const float* __restrict__ b2,
                                              float* __restrict__ out) {
    int g = blockIdx.x * blockDim.x + threadIdx.x;
    int c = g >> 5;
    int j = g & 31;
    if (c >= N_NODES || j >= OUT_F) return;
    float dic = dinv[c];
    float acc = dic * dic * h2[(size_t)c * OUT_F + j] + b2[j];
    int n = cnt[c];
    const uint2* seg = packed + (size_t)c * CAP;
    for (int k = 0; k < n; ++k) {
        uint2 pv = seg[k];                    // broadcast across lanes
        float nm = __uint_as_float(pv.y) * dinv[pv.x] * dic;
        acc = fmaf(nm, h2[(size_t)pv.x * OUT_F + j], acc);
    }
    out[(size_t)c * OUT_F + j] = acc;
}

// ---------------- launch ----------------

extern "C" void kernel_launch(void* const* d_in, const int* in_sizes, int n_in,
                              void* d_out, int out_size, void* d_ws, size_t ws_size,
                              hipStream_t stream) {
    const float* x  = (const float*)d_in[0];
    const int*   ei = (const int*)d_in[1];       // [2][E]
    const float* ew = (const float*)d_in[2];
    const float* W1 = (const float*)d_in[3];
    const float* b1 = (const float*)d_in[4];
    const float* W2 = (const float*)d_in[5];
    const float* b2 = (const float*)d_in[6];
    float* out = (float*)d_out;

    const int* row = ei;
    const int* col = ei + N_EDGES;

    char* p = (char*)d_ws;
    float* dinv    = (float*)p;    p += (size_t)N_NODES * 4;
    unsigned* h1b  = (unsigned*)p; p += (size_t)N_NODES * 64 * 4;   // bf16x2 packed
    float* h2      = (float*)p;    p += (size_t)N_NODES * OUT_F * 4;
    __bf16* hb     = (__bf16*)p;   p += (size_t)N_NODES * HID * 2;
    __bf16* w1p    = (__bf16*)p;   p += (size_t)F_IN * HID * 2;
    int* cursor    = (int*)p;      p += (size_t)N_NODES * 4;
    int* cnt       = (int*)p;      p += (size_t)N_NODES * 4;
    uint2* packed  = (uint2*)p;    p += (size_t)N_NODES * CAP * 8;

    // prep (W1 permute + cursor init)
    k_prep<<<(F_IN * HID + 255) / 256, 256, 0, stream>>>(W1, w1p, cursor);

    // fat kernel: gemm1 (MFMA/LDS pipeline) || fillb (atomic bucket CSR), 3:1 interleave
    k_fat<<<FAT_BLOCKS, 256, 0, stream>>>(x, w1p, hb, row, col, ew, cursor, packed);

    k_degdinv<<<(N_NODES + 255) / 256, 256, 0, stream>>>(cursor, packed, cnt, dinv);
    k_agg1<<<N_NODES / 2, 128, 0, stream>>>(packed, cnt, hb, dinv, b1, h1b);

    // layer 2
    k_gemm2<<<(N_NODES * 32 + 255) / 256, 256, 0, stream>>>(h1b, W2, h2);
    k_agg2<<<(N_NODES * 32 + 255) / 256, 256, 0, stream>>>(packed, cnt, h2, dinv, b2, out);
}

// Round 14
// 189.329 us; speedup vs baseline: 1.2282x; 1.0063x over previous
//
#include <hip/hip_runtime.h>

#define N_NODES 50000
#define N_EDGES 800000
#define F_IN    512
#define HID     128
#define OUT_F   20
#define CAP     48           // max in-degree capacity (mean 16, 8 sigma headroom)

#define BM  32
#define GEMM_BLOCKS ((N_NODES + BM - 1) / BM)   // 1563 = 521*3
#define FB_BLOCKS   521
#define FAT_BLOCKS  (FB_BLOCKS * 4)             // 2084: bid&3==3 -> fillb, else gemm

typedef __bf16 bf16x8 __attribute__((ext_vector_type(8)));
typedef float  f32x4  __attribute__((ext_vector_type(4)));

// ---------------- prep: W1 -> frag-ready permuted bf16 + cursor init (fused) ----------
// w1p index: (((kk*4 + g)*128 + cc)*8 + j); B-frag elem j of lane group g covers
// k = kk*32 + g*4 + (j&3) + 16*(j>>2), column cc.

__global__ void k_prep(const float* __restrict__ W1, __bf16* __restrict__ w1p,
                       int* __restrict__ cursor) {
    int gidx = blockIdx.x * blockDim.x + threadIdx.x;
    if (gidx < F_IN * HID) {
        int k  = gidx >> 7;
        int cc = gidx & (HID - 1);
        int kk = k >> 5;
        int r  = k & 31;
        int g  = (r & 15) >> 2;
        int j  = (r & 3) + ((r >> 4) << 2);
        w1p[((((size_t)kk * 4 + g) * 128 + cc) << 3) + j] = (__bf16)W1[gidx];
    }
    if (gidx < N_NODES) cursor[gidx] = gidx * CAP;
}

// ---------------- FAT kernel: gemm1 (MFMA, LDS-pipelined) || fillb (atomic CSR) -------
// r13 fix: BK=64 -> 16 KB LDS -> ~10 blocks/CU co-resident (was 5 at 32 KB, 30% occ);
// fillb path vectorized 4 edges/iter (int4/float4) -> 4 atomics in flight per thread.

__global__ __launch_bounds__(256) void k_fat(const float* __restrict__ x,
                                             const __bf16* __restrict__ w1p,
                                             __bf16* __restrict__ hb,
                                             const int* __restrict__ row,
                                             const int* __restrict__ col,
                                             const float* __restrict__ ew,
                                             int* __restrict__ cursor,
                                             uint2* __restrict__ packed) {
    __shared__ float As[2][BM * 64];      // 8 KB per buffer (gemm path only)
    const int tid = threadIdx.x;
    const int q   = blockIdx.x >> 2;
    const int r3  = blockIdx.x & 3;

    if (r3 == 3) {
        // ---------- fillb path: 4 edges/iter, 4 independent atomics in flight --------
        for (int v = q * 256 + tid; v < N_EDGES / 4; v += FB_BLOCKS * 256) {
            int4   c4 = ((const int4*)col)[v];
            int4   r4 = ((const int4*)row)[v];
            float4 w4 = ((const float4*)ew)[v];
            int p0 = atomicAdd(&cursor[c4.x], 1);
            int p1 = atomicAdd(&cursor[c4.y], 1);
            int p2 = atomicAdd(&cursor[c4.z], 1);
            int p3 = atomicAdd(&cursor[c4.w], 1);
            packed[p0] = make_uint2((unsigned)r4.x, __float_as_uint(w4.x));
            packed[p1] = make_uint2((unsigned)r4.y, __float_as_uint(w4.y));
            packed[p2] = make_uint2((unsigned)r4.z, __float_as_uint(w4.z));
            packed[p3] = make_uint2((unsigned)r4.w, __float_as_uint(w4.w));
        }
        return;
    }

    // ---------- gemm1 path ----------
    const int gemm_id = q * 3 + r3;       // 0..1562, each exactly once
    const int lane = tid & 63;
    const int wid  = tid >> 6;
    const int wm   = wid >> 1;            // row block of 16
    const int wn   = wid & 1;             // col block of 64
    const int r0   = gemm_id * BM;
    const int g    = lane >> 4;           // k-group 0..3
    const int l15  = lane & 15;

    const __bf16* pb = w1p + (((size_t)g * 128) + wn * 64 + l15) * 8;  // + kkg*4096

    f32x4 acc0 = {}, acc1 = {}, acc2 = {}, acc3 = {};

    // stage one BK=64 tile (512 x 16B chunks; 2 global_load_lds per thread)
    auto stage = [&](int buf, int k0) {
#pragma unroll
        for (int i = 0; i < 2; ++i) {
            int cb = wid * 64 + i * 256;          // wave-uniform chunk base
            int c  = cb + lane;                    // chunk id 0..511
            int rowc = c >> 4;                     // row 0..31 (16 chunks/row)
            int s    = c & 15;                     // 16B slot in row
            int gr = r0 + rowc;
            if (gr >= N_NODES) gr = N_NODES - 1;   // clamp (stores guarded later)
            const float* src = x + (size_t)gr * F_IN + k0 + ((s ^ (rowc & 7)) << 2);
            __builtin_amdgcn_global_load_lds(
                (const __attribute__((address_space(1))) void*)src,
                (__attribute__((address_space(3))) void*)(&As[buf][(size_t)cb * 4]),
                16, 0, 0);
        }
    };

    const int rowm = wm * 16 + l15;
    const int rbase = rowm * 64;
    const int rx = rowm & 7;

    stage(0, 0);
    __syncthreads();                      // drains vmcnt: tile 0 ready

#pragma unroll
    for (int t = 0; t < 8; ++t) {
        const int buf = t & 1;
        if (t < 7) stage(buf ^ 1, (t + 1) * 64);    // loads in flight across compute
#pragma unroll
        for (int kk = 0; kk < 2; ++kk) {
            // A frag: two b128 reads from swizzled LDS, cvt at consume
            int slo = ((kk * 8 + g)     ^ rx) << 2;
            int shi = ((kk * 8 + g + 4) ^ rx) << 2;
            f32x4 lo = *(const f32x4*)&As[buf][rbase + slo];
            f32x4 hi = *(const f32x4*)&As[buf][rbase + shi];
            union { __bf16 h[8]; bf16x8 v; } u;
            u.h[0] = (__bf16)lo[0]; u.h[1] = (__bf16)lo[1];
            u.h[2] = (__bf16)lo[2]; u.h[3] = (__bf16)lo[3];
            u.h[4] = (__bf16)hi[0]; u.h[5] = (__bf16)hi[1];
            u.h[6] = (__bf16)hi[2]; u.h[7] = (__bf16)hi[3];
            // B frags (L2-hot)
            const __bf16* bp = pb + (size_t)(t * 2 + kk) * 4096;
            bf16x8 b0 = *(const bf16x8*)(bp);
            bf16x8 b1 = *(const bf16x8*)(bp + 128);
            bf16x8 b2 = *(const bf16x8*)(bp + 256);
            bf16x8 b3 = *(const bf16x8*)(bp + 384);
            acc0 = __builtin_amdgcn_mfma_f32_16x16x32_bf16(u.v, b0, acc0, 0, 0, 0);
            acc1 = __builtin_amdgcn_mfma_f32_16x16x32_bf16(u.v, b1, acc1, 0, 0, 0);
            acc2 = __builtin_amdgcn_mfma_f32_16x16x32_bf16(u.v, b2, acc2, 0, 0, 0);
            acc3 = __builtin_amdgcn_mfma_f32_16x16x32_bf16(u.v, b3, acc3, 0, 0, 0);
        }
        __syncthreads();                  // next tile staged + all waves done reading
    }

    // epilogue: C/D col=lane&15, row=(lane>>4)*4+reg
    const int rb = r0 + wm * 16 + (g << 2);
#pragma unroll
    for (int rr = 0; rr < 4; ++rr) {
        int gr = rb + rr;
        if (gr < N_NODES) {
            __bf16* ho = hb + (size_t)gr * HID + wn * 64 + l15;
            ho[0]  = (__bf16)acc0[rr];
            ho[16] = (__bf16)acc1[rr];
            ho[32] = (__bf16)acc2[rr];
            ho[48] = (__bf16)acc3[rr];
        }
    }
}

// ---------------- deg/dinv from buckets (sequential, no atomics) ----------------

__global__ void k_degdinv(const int* __restrict__ cursor, const uint2* __restrict__ packed,
                          int* __restrict__ cnt, float* __restrict__ dinv) {
    int i = blockIdx.x * blockDim.x + threadIdx.x;
    if (i < N_NODES) {
        int n = cursor[i] - i * CAP;
        cnt[i] = n;
        const uint2* seg = packed + (size_t)i * CAP;
        float d = 1.0f;
        for (int k = 0; k < n; ++k) d += __uint_as_float(seg[k].y);
        dinv[i] = rsqrtf(d);   // d >= 1 always
    }
}

// ---------------- layer 1 aggregation: 1 wave per node, bf16x2 packed, on-the-fly norm --

__device__ inline float blo(unsigned v) { union { unsigned u; float f; } c; c.u = v << 16; return c.f; }
__device__ inline float bhi(unsigned v) { union { unsigned u; float f; } c; c.u = v & 0xffff0000u; return c.f; }

__global__ __launch_bounds__(128) void k_agg1(const uint2* __restrict__ packed,
                                              const int* __restrict__ cnt,
                                              const __bf16* __restrict__ hb,
                                              const float* __restrict__ dinv,
                                              const float* __restrict__ b1,
                                              unsigned* __restrict__ h1b) {
    __shared__ int   sr[2][64];
    __shared__ float sn[2][64];
    const int w    = threadIdx.x >> 6;
    const int lane = threadIdx.x & 63;
    const int c    = blockIdx.x * 2 + w;
    const unsigned* hbu = (const unsigned*)hb;

    float dic = dinv[c];
    unsigned sv = hbu[((size_t)c << 6) + lane];
    float a0 = dic * dic * blo(sv);
    float a1 = dic * dic * bhi(sv);
    int n = cnt[c];
    const uint2* seg = packed + (size_t)c * CAP;
    for (int base = 0; base < n; base += 64) {
        int m = n - base; if (m > 64) m = 64;
        if (lane < m) {                       // wave-synchronous, no barrier
            uint2 pv = seg[base + lane];
            sr[w][lane] = (int)pv.x;
            sn[w][lane] = __uint_as_float(pv.y) * dinv[pv.x] * dic;
        }
        for (int t = 0; t < m; ++t) {
            float nm = sn[w][t];
            unsigned v = hbu[((size_t)sr[w][t] << 6) + lane];
            a0 = fmaf(nm, blo(v), a0);
            a1 = fmaf(nm, bhi(v), a1);
        }
    }
    float2 bb = *(const float2*)(b1 + 2 * lane);
    a0 += bb.x; a1 += bb.y;
    union { __bf16 h[2]; unsigned u; } o;
    o.h[0] = (__bf16)(a0 > 0.f ? a0 : 0.f);
    o.h[1] = (__bf16)(a1 > 0.f ? a1 : 0.f);
    h1b[((size_t)c << 6) + lane] = o.u;
}

// ---------------- layer 2 GEMM: h2 = h1 @ W2  (50000x128 @ 128x20), h1 in bf16 ------

__global__ __launch_bounds__(256) void k_gemm2(const unsigned* __restrict__ h1b,
                                               const float* __restrict__ W2,
                                               float* __restrict__ h2) {
    int g = blockIdx.x * blockDim.x + threadIdx.x;
    int i = g >> 5;
    int j = g & 31;
    if (i >= N_NODES || j >= OUT_F) return;
    float acc = 0.f;
    const unsigned* hr = h1b + ((size_t)i << 6);
    for (int k2 = 0; k2 < 64; ++k2) {
        unsigned v = hr[k2];                  // 2 bf16 (k=2*k2, 2*k2+1)
        acc = fmaf(blo(v), W2[(2 * k2) * OUT_F + j],
              fmaf(bhi(v), W2[(2 * k2 + 1) * OUT_F + j], acc));
    }
    h2[(size_t)i * OUT_F + j] = acc;
}

// ---------------- layer 2 aggregation (on-the-fly norm) ----------------

__global__ __launch_bounds__(256) void k_agg2(const uint2* __restrict__ packed,
                                              const int* __restrict__ cnt,
                                              const float* __restrict__ h2,
                                              const float* __restrict__ dinv,
                                              const float* __restrict__ b2,
                                              float* __restrict__ out) {
    int g = blockIdx.x * blockDim.x + threadIdx.x;
    int c = g >> 5;
    int j = g & 31;
    if (c >= N_NODES || j >= OUT_F) return;
    float dic = dinv[c];
    float acc = dic * dic * h2[(size_t)c * OUT_F + j] + b2[j];
    int n = cnt[c];
    const uint2* seg = packed + (size_t)c * CAP;
    for (int k = 0; k < n; ++k) {
        uint2 pv = seg[k];                    // broadcast across lanes
        float nm = __uint_as_float(pv.y) * dinv[pv.x] * dic;
        acc = fmaf(nm, h2[(size_t)pv.x * OUT_F + j], acc);
    }
    out[(size_t)c * OUT_F + j] = acc;
}

// ---------------- launch ----------------

extern "C" void kernel_launch(void* const* d_in, const int* in_sizes, int n_in,
                              void* d_out, int out_size, void* d_ws, size_t ws_size,
                              hipStream_t stream) {
    const float* x  = (const float*)d_in[0];
    const int*   ei = (const int*)d_in[1];       // [2][E]
    const float* ew = (const float*)d_in[2];
    const float* W1 = (const float*)d_in[3];
    const float* b1 = (const float*)d_in[4];
    const float* W2 = (const float*)d_in[5];
    const float* b2 = (const float*)d_in[6];
    float* out = (float*)d_out;

    const int* row = ei;
    const int* col = ei + N_EDGES;

    char* p = (char*)d_ws;
    float* dinv    = (float*)p;    p += (size_t)N_NODES * 4;
    unsigned* h1b  = (unsigned*)p; p += (size_t)N_NODES * 64 * 4;   // bf16x2 packed
    float* h2      = (float*)p;    p += (size_t)N_NODES * OUT_F * 4;
    __bf16* hb     = (__bf16*)p;   p += (size_t)N_NODES * HID * 2;
    __bf16* w1p    = (__bf16*)p;   p += (size_t)F_IN * HID * 2;
    int* cursor    = (int*)p;      p += (size_t)N_NODES * 4;
    int* cnt       = (int*)p;      p += (size_t)N_NODES * 4;
    uint2* packed  = (uint2*)p;    p += (size_t)N_NODES * CAP * 8;

    // prep (W1 permute + cursor init)
    k_prep<<<(F_IN * HID + 255) / 256, 256, 0, stream>>>(W1, w1p, cursor);

    // fat kernel: gemm1 (MFMA/LDS pipeline) || fillb (atomic bucket CSR), 3:1 interleave
    k_fat<<<FAT_BLOCKS, 256, 0, stream>>>(x, w1p, hb, row, col, ew, cursor, packed);

    k_degdinv<<<(N_NODES + 255) / 256, 256, 0, stream>>>(cursor, packed, cnt, dinv);
    k_agg1<<<N_NODES / 2, 128, 0, stream>>>(packed, cnt, hb, dinv, b1, h1b);

    // layer 2
    k_gemm2<<<(N_NODES * 32 + 255) / 256, 256, 0, stream>>>(h1b, W2, h2);
    k_agg2<<<(N_NODES * 32 + 255) / 256, 256, 0, stream>>>(packed, cnt, h2, dinv, b2, out);
}

// Round 15
// 174.612 us; speedup vs baseline: 1.3318x; 1.0843x over previous
//
#include <hip/hip_runtime.h>

#define N_NODES 50000
#define N_EDGES 800000
#define F_IN    512
#define HID     128
#define OUT_F   20
#define CAP     48           // max in-degree capacity (mean 16, 8 sigma headroom)

#define BM  32
#define GEMM_BLOCKS ((N_NODES + BM - 1) / BM)   // 1563 = 521*3
#define FB_BLOCKS   521
#define FAT_BLOCKS  (FB_BLOCKS * 4)             // 2084: bid&3==3 -> fillb, else gemm

typedef __bf16 bf16x8 __attribute__((ext_vector_type(8)));
typedef float  f32x4  __attribute__((ext_vector_type(4)));

// ---------------- prep: W1 -> frag-ready permuted bf16 + cursor init (fused) ----------

__global__ void k_prep(const float* __restrict__ W1, __bf16* __restrict__ w1p,
                       int* __restrict__ cursor) {
    int gidx = blockIdx.x * blockDim.x + threadIdx.x;
    if (gidx < F_IN * HID) {
        int k  = gidx >> 7;
        int cc = gidx & (HID - 1);
        int kk = k >> 5;
        int r  = k & 31;
        int g  = (r & 15) >> 2;
        int j  = (r & 3) + ((r >> 4) << 2);
        w1p[((((size_t)kk * 4 + g) * 128 + cc) << 3) + j] = (__bf16)W1[gidx];
    }
    if (gidx < N_NODES) cursor[gidx] = gidx * CAP;
}

// ---------------- FAT kernel: gemm1 (MFMA, LDS-pipelined) || fillb (atomic CSR) -------

__global__ __launch_bounds__(256) void k_fat(const float* __restrict__ x,
                                             const __bf16* __restrict__ w1p,
                                             __bf16* __restrict__ hb,
                                             const int* __restrict__ row,
                                             const int* __restrict__ col,
                                             const float* __restrict__ ew,
                                             int* __restrict__ cursor,
                                             uint2* __restrict__ packed) {
    __shared__ float As[2][BM * 64];      // 8 KB per buffer (gemm path only)
    const int tid = threadIdx.x;
    const int q   = blockIdx.x >> 2;
    const int r3  = blockIdx.x & 3;

    if (r3 == 3) {
        // ---------- fillb path: 4 edges/iter, 4 independent atomics in flight --------
        for (int v = q * 256 + tid; v < N_EDGES / 4; v += FB_BLOCKS * 256) {
            int4   c4 = ((const int4*)col)[v];
            int4   r4 = ((const int4*)row)[v];
            float4 w4 = ((const float4*)ew)[v];
            int p0 = atomicAdd(&cursor[c4.x], 1);
            int p1 = atomicAdd(&cursor[c4.y], 1);
            int p2 = atomicAdd(&cursor[c4.z], 1);
            int p3 = atomicAdd(&cursor[c4.w], 1);
            packed[p0] = make_uint2((unsigned)r4.x, __float_as_uint(w4.x));
            packed[p1] = make_uint2((unsigned)r4.y, __float_as_uint(w4.y));
            packed[p2] = make_uint2((unsigned)r4.z, __float_as_uint(w4.z));
            packed[p3] = make_uint2((unsigned)r4.w, __float_as_uint(w4.w));
        }
        return;
    }

    // ---------- gemm1 path ----------
    const int gemm_id = q * 3 + r3;       // 0..1562, each exactly once
    const int lane = tid & 63;
    const int wid  = tid >> 6;
    const int wm   = wid >> 1;            // row block of 16
    const int wn   = wid & 1;             // col block of 64
    const int r0   = gemm_id * BM;
    const int g    = lane >> 4;           // k-group 0..3
    const int l15  = lane & 15;

    const __bf16* pb = w1p + (((size_t)g * 128) + wn * 64 + l15) * 8;  // + kkg*4096

    f32x4 acc0 = {}, acc1 = {}, acc2 = {}, acc3 = {};

    auto stage = [&](int buf, int k0) {
#pragma unroll
        for (int i = 0; i < 2; ++i) {
            int cb = wid * 64 + i * 256;          // wave-uniform chunk base
            int c  = cb + lane;                    // chunk id 0..511
            int rowc = c >> 4;                     // row 0..31 (16 chunks/row)
            int s    = c & 15;                     // 16B slot in row
            int gr = r0 + rowc;
            if (gr >= N_NODES) gr = N_NODES - 1;   // clamp (stores guarded later)
            const float* src = x + (size_t)gr * F_IN + k0 + ((s ^ (rowc & 7)) << 2);
            __builtin_amdgcn_global_load_lds(
                (const __attribute__((address_space(1))) void*)src,
                (__attribute__((address_space(3))) void*)(&As[buf][(size_t)cb * 4]),
                16, 0, 0);
        }
    };

    const int rowm = wm * 16 + l15;
    const int rbase = rowm * 64;
    const int rx = rowm & 7;

    stage(0, 0);
    __syncthreads();                      // drains vmcnt: tile 0 ready

#pragma unroll
    for (int t = 0; t < 8; ++t) {
        const int buf = t & 1;
        if (t < 7) stage(buf ^ 1, (t + 1) * 64);    // loads in flight across compute
#pragma unroll
        for (int kk = 0; kk < 2; ++kk) {
            int slo = ((kk * 8 + g)     ^ rx) << 2;
            int shi = ((kk * 8 + g + 4) ^ rx) << 2;
            f32x4 lo = *(const f32x4*)&As[buf][rbase + slo];
            f32x4 hi = *(const f32x4*)&As[buf][rbase + shi];
            union { __bf16 h[8]; bf16x8 v; } u;
            u.h[0] = (__bf16)lo[0]; u.h[1] = (__bf16)lo[1];
            u.h[2] = (__bf16)lo[2]; u.h[3] = (__bf16)lo[3];
            u.h[4] = (__bf16)hi[0]; u.h[5] = (__bf16)hi[1];
            u.h[6] = (__bf16)hi[2]; u.h[7] = (__bf16)hi[3];
            const __bf16* bp = pb + (size_t)(t * 2 + kk) * 4096;
            bf16x8 b0 = *(const bf16x8*)(bp);
            bf16x8 b1 = *(const bf16x8*)(bp + 128);
            bf16x8 b2 = *(const bf16x8*)(bp + 256);
            bf16x8 b3 = *(const bf16x8*)(bp + 384);
            acc0 = __builtin_amdgcn_mfma_f32_16x16x32_bf16(u.v, b0, acc0, 0, 0, 0);
            acc1 = __builtin_amdgcn_mfma_f32_16x16x32_bf16(u.v, b1, acc1, 0, 0, 0);
            acc2 = __builtin_amdgcn_mfma_f32_16x16x32_bf16(u.v, b2, acc2, 0, 0, 0);
            acc3 = __builtin_amdgcn_mfma_f32_16x16x32_bf16(u.v, b3, acc3, 0, 0, 0);
        }
        __syncthreads();
    }

    const int rb = r0 + wm * 16 + (g << 2);
#pragma unroll
    for (int rr = 0; rr < 4; ++rr) {
        int gr = rb + rr;
        if (gr < N_NODES) {
            __bf16* ho = hb + (size_t)gr * HID + wn * 64 + l15;
            ho[0]  = (__bf16)acc0[rr];
            ho[16] = (__bf16)acc1[rr];
            ho[32] = (__bf16)acc2[rr];
            ho[48] = (__bf16)acc3[rr];
        }
    }
}

// ---------------- deg/dinv from buckets (sequential, no atomics) ----------------

__global__ void k_degdinv(const int* __restrict__ cursor, const uint2* __restrict__ packed,
                          int* __restrict__ cnt, float* __restrict__ dinv) {
    int i = blockIdx.x * blockDim.x + threadIdx.x;
    if (i < N_NODES) {
        int n = cursor[i] - i * CAP;
        cnt[i] = n;
        const uint2* seg = packed + (size_t)i * CAP;
        float d = 1.0f;
        for (int k = 0; k < n; ++k) d += __uint_as_float(seg[k].y);
        dinv[i] = rsqrtf(d);   // d >= 1 always
    }
}

// ---------------- fused agg1 + relu + gemm2: h2[c] = relu(agg1(c)+b1) @ W2 ------------
// 1 wave per node. Gather phase as before; norm written BACK into packed[].y so
// agg2 skips its per-edge dinv gather. Then h1 (fp32) -> 1 KB LDS (wave-sync),
// 20-col dot split 3 ways across lanes 0-59 (43 k-steps each), 2-bpermute reduce.

__device__ inline float blo(unsigned v) { union { unsigned u; float f; } c; c.u = v << 16; return c.f; }
__device__ inline float bhi(unsigned v) { union { unsigned u; float f; } c; c.u = v & 0xffff0000u; return c.f; }

__global__ __launch_bounds__(128) void k_agg1g2(uint2* __restrict__ packed,
                                                const int* __restrict__ cnt,
                                                const __bf16* __restrict__ hb,
                                                const float* __restrict__ dinv,
                                                const float* __restrict__ b1,
                                                const float* __restrict__ W2,
                                                float* __restrict__ h2) {
    __shared__ int   sr[2][64];
    __shared__ float sn[2][64];
    __shared__ float sh1[2][128];
    const int w    = threadIdx.x >> 6;
    const int lane = threadIdx.x & 63;
    const int c    = blockIdx.x * 2 + w;
    const unsigned* hbu = (const unsigned*)hb;

    float dic = dinv[c];
    unsigned sv = hbu[((size_t)c << 6) + lane];
    float a0 = dic * dic * blo(sv);
    float a1 = dic * dic * bhi(sv);
    int n = cnt[c];
    uint2* seg = packed + (size_t)c * CAP;
    for (int base = 0; base < n; base += 64) {
        int m = n - base; if (m > 64) m = 64;
        if (lane < m) {                       // wave-synchronous, no barrier
            uint2 pv = seg[base + lane];
            float nm = __uint_as_float(pv.y) * dinv[pv.x] * dic;
            sr[w][lane] = (int)pv.x;
            sn[w][lane] = nm;
            seg[base + lane] = make_uint2(pv.x, __float_as_uint(nm));  // norm write-back
        }
        for (int t = 0; t < m; ++t) {
            float nm = sn[w][t];
            unsigned v = hbu[((size_t)sr[w][t] << 6) + lane];
            a0 = fmaf(nm, blo(v), a0);
            a1 = fmaf(nm, bhi(v), a1);
        }
    }
    float2 bb = *(const float2*)(b1 + 2 * lane);
    a0 += bb.x; a1 += bb.y;
    // relu + stash h1 in LDS (wave-synchronous: same wave writes then reads)
    sh1[w][2 * lane]     = a0 > 0.f ? a0 : 0.f;
    sh1[w][2 * lane + 1] = a1 > 0.f ? a1 : 0.f;

    // h2[c][j] = sum_k h1[k] * W2[k][j], j = lane%20, 3-way k-split over lanes 0-59
    const int part = lane / 20;               // 0..3 (60-63 idle)
    const int j    = lane - part * 20;
    float s = 0.f;
    if (part < 3) {
        const int kbeg = part * 43;
        const int kend = (part == 2) ? 128 : kbeg + 43;
#pragma unroll 4
        for (int k = kbeg; k < kend; ++k)
            s = fmaf(sh1[w][k], W2[k * OUT_F + j], s);
    }
    float s1 = __shfl(s, lane + 20);
    float s2 = __shfl(s, lane + 40);
    if (lane < 20) h2[(size_t)c * OUT_F + lane] = s + s1 + s2;
}

// ---------------- layer 2 aggregation: norm precomputed in packed[].y ----------------

__global__ __launch_bounds__(256) void k_agg2(const uint2* __restrict__ packed,
                                              const int* __restrict__ cnt,
                                              const float* __restrict__ h2,
                                              const float* __restrict__ dinv,
                                              const float* __restrict__ b2,
                                              float* __restrict__ out) {
    int g = blockIdx.x * blockDim.x + threadIdx.x;
    int c = g >> 5;
    int j = g & 31;
    if (c >= N_NODES || j >= OUT_F) return;
    float dic = dinv[c];
    float acc = dic * dic * h2[(size_t)c * OUT_F + j] + b2[j];
    int n = cnt[c];
    const uint2* seg = packed + (size_t)c * CAP;
    for (int k = 0; k < n; ++k) {
        uint2 pv = seg[k];                    // broadcast across lanes
        acc = fmaf(__uint_as_float(pv.y), h2[(size_t)pv.x * OUT_F + j], acc);
    }
    out[(size_t)c * OUT_F + j] = acc;
}

// ---------------- launch ----------------

extern "C" void kernel_launch(void* const* d_in, const int* in_sizes, int n_in,
                              void* d_out, int out_size, void* d_ws, size_t ws_size,
                              hipStream_t stream) {
    const float* x  = (const float*)d_in[0];
    const int*   ei = (const int*)d_in[1];       // [2][E]
    const float* ew = (const float*)d_in[2];
    const float* W1 = (const float*)d_in[3];
    const float* b1 = (const float*)d_in[4];
    const float* W2 = (const float*)d_in[5];
    const float* b2 = (const float*)d_in[6];
    float* out = (float*)d_out;

    const int* row = ei;
    const int* col = ei + N_EDGES;

    char* p = (char*)d_ws;
    float* dinv    = (float*)p;    p += (size_t)N_NODES * 4;
    float* h2      = (float*)p;    p += (size_t)N_NODES * OUT_F * 4;
    __bf16* hb     = (__bf16*)p;   p += (size_t)N_NODES * HID * 2;
    __bf16* w1p    = (__bf16*)p;   p += (size_t)F_IN * HID * 2;
    int* cursor    = (int*)p;      p += (size_t)N_NODES * 4;
    int* cnt       = (int*)p;      p += (size_t)N_NODES * 4;
    uint2* packed  = (uint2*)p;    p += (size_t)N_NODES * CAP * 8;

    // prep (W1 permute + cursor init)
    k_prep<<<(F_IN * HID + 255) / 256, 256, 0, stream>>>(W1, w1p, cursor);

    // fat kernel: gemm1 (MFMA/LDS pipeline) || fillb (atomic bucket CSR), 3:1 interleave
    k_fat<<<FAT_BLOCKS, 256, 0, stream>>>(x, w1p, hb, row, col, ew, cursor, packed);

    k_degdinv<<<(N_NODES + 255) / 256, 256, 0, stream>>>(cursor, packed, cnt, dinv);

    // fused: agg1 + bias + relu + (h1 @ W2) -> h2 ; also writes norm back into packed
    k_agg1g2<<<N_NODES / 2, 128, 0, stream>>>(packed, cnt, hb, dinv, b1, W2, h2);

    // layer 2 aggregation
    k_agg2<<<(N_NODES * 32 + 255) / 256, 256, 0, stream>>>(packed, cnt, h2, dinv, b2, out);
}